// Round 7
// baseline (6621.661 us; speedup 1.0000x reference)
//
#include <hip/hip_runtime.h>
#include <hip/hip_cooperative_groups.h>
#include <math.h>

// GRUDecoder (NRI decoder) on MI355X — round 7: persistent cooperative kernel.
// Same fp16 MFMA math as round 6 (passed, absmax 4.39e-3). All 39 steps run in
// ONE cooperative kernel (512 blocks x 512 thr, grid.sync between phases),
// eliminating 78 launch/drain boundaries; gru phase gets 8-wave TLP.
// Fallback to per-step launches if cooperative launch is unavailable.

namespace {
constexpr int kB = 16, kT = 40, kTS = 39, kN = 64, kDin = 64, kH = 256;
constexpr int kE = kN * (kN - 1);   // 4032
constexpr int kBN = kB * kN;        // 1024
constexpr int kDout = 64;
}

namespace cgns = cooperative_groups;

typedef _Float16 half8 __attribute__((ext_vector_type(8)));
typedef float f32x4 __attribute__((ext_vector_type(4)));

__device__ __forceinline__ float sigm(float x) { return 1.f / (1.f + expf(-x)); }

__device__ __forceinline__ unsigned short f2h(float x) {
    _Float16 h = (_Float16)x;          // v_cvt_f16_f32, RNE
    return __builtin_bit_cast(unsigned short, h);
}

__device__ __forceinline__ uint4 pack8h(const float* x) {
    unsigned us[8];
    #pragma unroll
    for (int q = 0; q < 8; ++q) us[q] = f2h(x[q]);
    uint4 p;
    p.x = us[0] | (us[1] << 16); p.y = us[2] | (us[3] << 16);
    p.z = us[4] | (us[5] << 16); p.w = us[6] | (us[7] << 16);
    return p;
}

struct FParams {
    const float* inputs;
    const float* b1; const float* b2;
    const float* ts; const int* edge_at;
    const unsigned short* W2f;
    const unsigned short* Wri;
    const unsigned short* Wnh;
    const unsigned short* Wnx;
    const unsigned short* Wuv;
    const float* bri; const float* bhn; const float* bin_;
    float* U; float* V; float* agg; float* hh;
};

// ---------------- setup: edge table, type sums, all weights -> fp16 ---------
__global__ void setup_kernel(
    const float* __restrict__ rel_rec, const float* __restrict__ rel_send,
    const float* __restrict__ rel_types, const float* __restrict__ W2,
    const float* __restrict__ Whr, const float* __restrict__ Whi,
    const float* __restrict__ Whn, const float* __restrict__ Wir,
    const float* __restrict__ Wii, const float* __restrict__ Win,
    const float* __restrict__ W1,
    const float* __restrict__ bir, const float* __restrict__ bhr,
    const float* __restrict__ bii, const float* __restrict__ bhi,
    const float* __restrict__ fc1w, const float* __restrict__ fc2w,
    const float* __restrict__ fc3w,
    int* __restrict__ edge_at, float* __restrict__ ts,
    unsigned short* __restrict__ W2f,
    unsigned short* __restrict__ Wri,
    unsigned short* __restrict__ Wnh,
    unsigned short* __restrict__ Wnx,
    unsigned short* __restrict__ Wuv,
    unsigned short* __restrict__ F1, unsigned short* __restrict__ F2,
    unsigned short* __restrict__ F3,
    float* __restrict__ bri) {
    int idx = blockIdx.x * 256 + threadIdx.x;
    if (idx < kE) {
        int si = 0, ri = 0;
        for (int n = 0; n < kN; ++n) {
            if (rel_send[idx * kN + n] > 0.5f) si = n;
            if (rel_rec[idx * kN + n] > 0.5f) ri = n;
        }
        edge_at[ri * kN + si] = idx;
    }
    if (idx < kB * kE) ts[idx] = rel_types[2 * idx] + rel_types[2 * idx + 1];
    if (idx < kH * kH) {
        W2f[idx] = f2h(W2[idx]);
        Wnh[idx] = f2h(Whn[idx]);
        F1[idx] = f2h(fc1w[idx]);
        F2[idx] = f2h(fc2w[idx]);
    }
    if (idx < 512 * 320) {  // Wri = [[Whr|Wir],[Whi|Wii]]  rows x K=320
        int row = idx / 320, k = idx - row * 320;
        float v;
        if (row < 256) v = (k < kH) ? Whr[row * kH + k] : Wir[row * kDin + k - kH];
        else { int o = row - 256; v = (k < kH) ? Whi[o * kH + k] : Wii[o * kDin + k - kH]; }
        Wri[idx] = f2h(v);
    }
    if (idx < kH * kDin) Wnx[idx] = f2h(Win[idx]);
    if (idx < 512 * 256) {  // Wuv: row<256 -> U (W1 cols 0..255), else V
        int row = idx >> 8, k = idx & 255;
        float v = (row < 256) ? W1[row * 512 + k] : W1[(row - 256) * 512 + 256 + k];
        Wuv[idx] = f2h(v);
    }
    if (idx < kDout * kH) F3[idx] = f2h(fc3w[idx]);
    if (idx < 256) bri[idx] = bir[idx] + bhr[idx];
    else if (idx < 512) bri[idx] = bii[idx - 256] + bhi[idx - 256];
}

// ---------------- edge phase: 512 blocks x 512 thr, 2 (b,j) pairs/block ----
__device__ __forceinline__ void edge_phase(const FParams& p) {
    __shared__ __align__(16) unsigned short h1[kN * kH];  // 32 KiB, swizzled
    __shared__ float vjb[kH];
    __shared__ float tss[kN];
    const int tid = threadIdx.x;
    const int lane = tid & 63, w = tid >> 6;      // 8 waves
    const int mrow = lane & 15, mq = lane >> 4;

    #pragma unroll 1
    for (int pr = 0; pr < 2; ++pr) {
        const int blk = blockIdx.x * 2 + pr;
        const int b = blk >> 6, j = blk & 63;
        if (tid < kN) {
            int e = p.edge_at[j * kN + tid];
            tss[tid] = (e < 0) ? 0.f : p.ts[b * kE + e];
        }
        if (tid < kH) vjb[tid] = p.V[(size_t)(b * kN + j) * kH + tid] + p.b1[tid];
        __syncthreads();

        // build h1 = relu(U_i + vjb) as fp16, swizzle byte ^= (row&7)<<4
        {
            const int o = tid & 31, i0 = tid >> 5;   // octet o, row seed i0 (0..15)
            const int k0 = o * 8;
            const float4 vj0 = *(const float4*)&vjb[k0];
            const float4 vj1 = *(const float4*)&vjb[k0 + 4];
            #pragma unroll
            for (int pp = 0; pp < 4; ++pp) {
                const int i = i0 + 16 * pp;
                const float4* up = (const float4*)(p.U + (size_t)(b * kN + i) * kH + k0);
                float4 f0 = up[0], f1 = up[1];
                float x[8] = {f0.x + vj0.x, f0.y + vj0.y, f0.z + vj0.z, f0.w + vj0.w,
                              f1.x + vj1.x, f1.y + vj1.y, f1.z + vj1.z, f1.w + vj1.w};
                #pragma unroll
                for (int q = 0; q < 8; ++q) x[q] = (i == j) ? 0.f : fmaxf(x[q], 0.f);
                const int byte = i * 512 + ((k0 * 2) ^ ((i & 7) << 4));
                *(uint4*)((char*)h1 + byte) = pack8h(x);
            }
        }
        __syncthreads();

        // MFMA: 8 waves x 2 nf (32 cols/wave), full M=64
        f32x4 acc[4][2];
        #pragma unroll
        for (int mf = 0; mf < 4; ++mf)
            #pragma unroll
            for (int nf = 0; nf < 2; ++nf) acc[mf][nf] = (f32x4){0.f, 0.f, 0.f, 0.f};

        const unsigned short* Wp = p.W2f + (size_t)(w * 32 + mrow) * kH + mq * 8;
        #pragma unroll
        for (int kt = 0; kt < 8; ++kt) {
            const int k0 = kt * 32;
            half8 a[4], bb[2];
            #pragma unroll
            for (int mf = 0; mf < 4; ++mf) {
                const int r = mf * 16 + mrow;
                const int byte = r * 512 + (((k0 + mq * 8) * 2) ^ ((r & 7) << 4));
                a[mf] = *(const half8*)((const char*)h1 + byte);
            }
            #pragma unroll
            for (int nf = 0; nf < 2; ++nf)
                bb[nf] = *(const half8*)(Wp + nf * 16 * kH + k0);
            #pragma unroll
            for (int mf = 0; mf < 4; ++mf)
                #pragma unroll
                for (int nf = 0; nf < 2; ++nf)
                    acc[mf][nf] = __builtin_amdgcn_mfma_f32_16x16x32_f16(
                        a[mf], bb[nf], acc[mf][nf], 0, 0, 0);
        }

        // epilogue: relu(+b2), ts-weight, reduce over senders
        float tsr[16];
        #pragma unroll
        for (int mf = 0; mf < 4; ++mf)
            #pragma unroll
            for (int r = 0; r < 4; ++r)
                tsr[mf * 4 + r] = tss[mf * 16 + mq * 4 + r];
        #pragma unroll
        for (int nf = 0; nf < 2; ++nf) {
            const int col = w * 32 + nf * 16 + mrow;
            const float bv = p.b2[col];
            float s = 0.f;
            #pragma unroll
            for (int mf = 0; mf < 4; ++mf)
                #pragma unroll
                for (int r = 0; r < 4; ++r)
                    s += tsr[mf * 4 + r] * fmaxf(acc[mf][nf][r] + bv, 0.f);
            s += __shfl_xor(s, 16);
            s += __shfl_xor(s, 32);
            if (lane < 16) p.agg[(size_t)(b * kN + j) * kH + col] = s;
        }
        __syncthreads();   // protect h1/vjb/tss before next pair restages
    }
}

// ---------------- gru phase: blocks 0..63, 512 thr, 16 rows/block ----------
__device__ __forceinline__ void gru_phase(const FParams& p, int t) {
    __shared__ __align__(16) unsigned short Zf[16 * 320];  // 10 KiB
    __shared__ __align__(16) unsigned short Hf[16 * 256];  // 8 KiB
    const int m0 = blockIdx.x * 16;
    const int tid = threadIdx.x;
    const float* hprev = p.hh + (size_t)t * kBN * kH;
    float* hnew = p.hh + (size_t)(t + 1) * kBN * kH;

    // stage Z = [agg | x]: 16 rows x 40 octets, swizzled rows of 640 B
    for (int c = tid; c < 16 * 40; c += 512) {
        const int r = c / 40, g = c - r * 40;
        float x[8];
        if (g < 32) {
            const float* ap = p.agg + (size_t)(m0 + r) * kH + g * 8;
            *(float4*)&x[0] = ((const float4*)ap)[0];
            *(float4*)&x[4] = ((const float4*)ap)[1];
        } else {
            const int grow = m0 + r, b = grow >> 6, n = grow & 63;
            const float* xp = p.inputs + ((size_t)(b * kT + t) * kN + n) * kDin + (g - 32) * 8;
            *(float4*)&x[0] = ((const float4*)xp)[0];
            *(float4*)&x[4] = ((const float4*)xp)[1];
        }
        const int byte = r * 640 + ((g ^ (r & 7)) << 4);
        *(uint4*)((char*)Zf + byte) = pack8h(x);
    }
    __syncthreads();

    const int lane = tid & 63, w = tid >> 6;   // 8 waves
    const int mrow = lane & 15, mq = lane >> 4;

    // GEMM1: 2 nf per wave (8 waves x 32 cols = 256)
    #pragma unroll
    for (int nf = 0; nf < 2; ++nf) {
        const int col = w * 32 + nf * 16 + mrow;
        const unsigned short* WR = p.Wri + (size_t)col * 320 + mq * 8;
        const unsigned short* WI = p.Wri + (size_t)(256 + col) * 320 + mq * 8;
        const unsigned short* WNh = p.Wnh + (size_t)col * kH + mq * 8;
        const unsigned short* WNx = p.Wnx + (size_t)col * kDin + mq * 8;

        f32x4 aR = {0.f,0.f,0.f,0.f}, aI = {0.f,0.f,0.f,0.f};
        f32x4 aNH = {0.f,0.f,0.f,0.f}, aNX = {0.f,0.f,0.f,0.f};

        half8 rw[2][3];   // ring-2 [slot][gate: r,i,n]
        rw[0][0] = *(const half8*)(WR);
        rw[0][1] = *(const half8*)(WI);
        rw[0][2] = *(const half8*)(WNh);
        #pragma unroll
        for (int kt = 0; kt < 10; ++kt) {
            const int cur = kt & 1;
            if (kt + 1 < 10) {
                const int k1 = (kt + 1) * 32;
                rw[cur^1][0] = *(const half8*)(WR + k1);
                rw[cur^1][1] = *(const half8*)(WI + k1);
                if (kt + 1 < 8) rw[cur^1][2] = *(const half8*)(WNh + k1);
                else            rw[cur^1][2] = *(const half8*)(WNx + (k1 - 256));
            }
            const int g = kt * 4 + mq;
            const int byte = mrow * 640 + ((g ^ (mrow & 7)) << 4);
            half8 zf = *(const half8*)((const char*)Zf + byte);
            aR = __builtin_amdgcn_mfma_f32_16x16x32_f16(zf, rw[cur][0], aR, 0, 0, 0);
            aI = __builtin_amdgcn_mfma_f32_16x16x32_f16(zf, rw[cur][1], aI, 0, 0, 0);
            if (kt < 8) aNH = __builtin_amdgcn_mfma_f32_16x16x32_f16(zf, rw[cur][2], aNH, 0, 0, 0);
            else        aNX = __builtin_amdgcn_mfma_f32_16x16x32_f16(zf, rw[cur][2], aNX, 0, 0, 0);
        }

        const float brv = p.bri[col], biv = p.bri[256 + col];
        const float bhnv = p.bhn[col], binv = p.bin_[col];
        #pragma unroll
        for (int reg = 0; reg < 4; ++reg) {
            const int lr = mq * 4 + reg;
            const int grow = m0 + lr;
            float rg = sigm(aR[reg] + brv);
            float ig = sigm(aI[reg] + biv);
            float ng = tanhf(aNX[reg] + binv + rg * (aNH[reg] + bhnv));
            float h2 = (1.f - ig) * ng + ig * hprev[(size_t)grow * kH + col];
            hnew[(size_t)grow * kH + col] = h2;
            const int byte = lr * 512 + (((col >> 3) ^ (lr & 7)) << 4) + (col & 7) * 2;
            *(unsigned short*)((char*)Hf + byte) = f2h(h2);
        }
    }
    __syncthreads();

    // GEMM2: 4 nf per wave (8 waves x 64 cols = 512) -> U,V
    #pragma unroll
    for (int nf = 0; nf < 4; ++nf) {
        const int col = w * 64 + nf * 16 + mrow;
        const unsigned short* Wp = p.Wuv + (size_t)col * kH + mq * 8;
        f32x4 aUV = {0.f, 0.f, 0.f, 0.f};
        half8 rw[2];
        rw[0] = *(const half8*)(Wp);
        #pragma unroll
        for (int kt = 0; kt < 8; ++kt) {
            const int cur = kt & 1;
            if (kt + 1 < 8) rw[cur^1] = *(const half8*)(Wp + (kt + 1) * 32);
            const int g = kt * 4 + mq;
            const int byte = mrow * 512 + ((g ^ (mrow & 7)) << 4);
            half8 zf = *(const half8*)((const char*)Hf + byte);
            aUV = __builtin_amdgcn_mfma_f32_16x16x32_f16(zf, rw[cur], aUV, 0, 0, 0);
        }
        #pragma unroll
        for (int reg = 0; reg < 4; ++reg) {
            const int grow = m0 + mq * 4 + reg;
            const float v = aUV[reg];
            if (col < 256) p.U[(size_t)grow * kH + col] = v;
            else p.V[(size_t)grow * kH + col - 256] = v;
        }
    }
}

// ---------------- persistent cooperative kernel: all 39 steps ----------------
__global__ __launch_bounds__(512, 4)
void fused_kernel(FParams p) {
    cgns::grid_group grid = cgns::this_grid();
    for (int t = 0; t < kTS; ++t) {
        edge_phase(p);
        grid.sync();
        if (blockIdx.x < 64) gru_phase(p, t);
        grid.sync();
    }
}

// ---------------- fallback per-step kernels (same phases) ----------------
__global__ __launch_bounds__(512, 4)
void edge_step_kernel(FParams p) { edge_phase(p); }

__global__ __launch_bounds__(512, 4)
void gru_step_kernel(FParams p, int t) { gru_phase(p, t); }

// ---------------- batched output MLP (fp16 MFMA), unchanged from r6 ---------
__global__ __launch_bounds__(256, 4)
void out_kernel(const float* __restrict__ hist,
                const unsigned short* __restrict__ F1,
                const unsigned short* __restrict__ F2,
                const unsigned short* __restrict__ F3,
                const float* __restrict__ fc1b, const float* __restrict__ fc2b,
                const float* __restrict__ fc3b, float* __restrict__ out) {
    __shared__ __align__(16) unsigned short Af[32 * 256];  // 16 KiB
    __shared__ __align__(16) unsigned short Bf[32 * 256];  // 16 KiB
    const int m0 = blockIdx.x * 32;
    const int tid = threadIdx.x;

    #pragma unroll
    for (int it = 0; it < 4; ++it) {
        const int c = tid + it * 256;
        const int r = c >> 5, o = c & 31;
        const float* ap = hist + (size_t)(m0 + r) * kH + o * 8;
        float x[8];
        *(float4*)&x[0] = ((const float4*)ap)[0];
        *(float4*)&x[4] = ((const float4*)ap)[1];
        const int byte = r * 512 + ((o << 4) ^ ((r & 7) << 4));
        *(uint4*)((char*)Af + byte) = pack8h(x);
    }
    __syncthreads();

    const int lane = tid & 63, w = tid >> 6;
    const int mrow = lane & 15, mq = lane >> 4;

    #define LAYER(SRC, WW, BIAS, DST)                                           \
    {                                                                           \
        f32x4 acc[2][4];                                                        \
        _Pragma("unroll")                                                       \
        for (int m = 0; m < 2; ++m)                                             \
            _Pragma("unroll")                                                   \
            for (int nf = 0; nf < 4; ++nf) acc[m][nf] = (f32x4){0.f,0.f,0.f,0.f};\
        const unsigned short* wb = WW + (size_t)(w * 64 + mrow) * kH + mq * 8;  \
        _Pragma("unroll")                                                       \
        for (int kt = 0; kt < 8; ++kt) {                                        \
            const int k0 = kt * 32;                                             \
            half8 zf[2], bb[4];                                                 \
            _Pragma("unroll")                                                   \
            for (int m = 0; m < 2; ++m) {                                       \
                const int r = m * 16 + mrow;                                    \
                const int byte = r * 512 + (((k0 + mq * 8) * 2) ^ ((r & 7) << 4)); \
                zf[m] = *(const half8*)((const char*)SRC + byte);               \
            }                                                                   \
            _Pragma("unroll")                                                   \
            for (int nf = 0; nf < 4; ++nf)                                      \
                bb[nf] = *(const half8*)(wb + nf * 16 * kH + k0);               \
            _Pragma("unroll")                                                   \
            for (int m = 0; m < 2; ++m)                                         \
                _Pragma("unroll")                                               \
                for (int nf = 0; nf < 4; ++nf)                                  \
                    acc[m][nf] = __builtin_amdgcn_mfma_f32_16x16x32_f16(        \
                        zf[m], bb[nf], acc[m][nf], 0, 0, 0);                    \
        }                                                                       \
        _Pragma("unroll")                                                       \
        for (int m = 0; m < 2; ++m)                                             \
            _Pragma("unroll")                                                   \
            for (int nf = 0; nf < 4; ++nf) {                                    \
                const int col = w * 64 + nf * 16 + mrow;                        \
                const float bv = BIAS[col];                                     \
                _Pragma("unroll")                                               \
                for (int reg = 0; reg < 4; ++reg) {                             \
                    const int lr = m * 16 + mq * 4 + reg;                       \
                    float v = fmaxf(acc[m][nf][reg] + bv, 0.f);                 \
                    const int byte = lr * 512 + (((col >> 3) ^ (lr & 7)) << 4) + (col & 7) * 2; \
                    *(unsigned short*)((char*)DST + byte) = f2h(v);             \
                }                                                               \
            }                                                                   \
        __syncthreads();                                                        \
    }

    LAYER(Af, F1, fc1b, Bf)
    LAYER(Bf, F2, fc2b, Af)

    {
        f32x4 acc[2];
        acc[0] = (f32x4){0.f, 0.f, 0.f, 0.f};
        acc[1] = (f32x4){0.f, 0.f, 0.f, 0.f};
        const int row = w * 16 + mrow;
        const unsigned short* wb = F3 + (size_t)row * kH + mq * 8;
        #pragma unroll
        for (int kt = 0; kt < 8; ++kt) {
            const int k0 = kt * 32;
            half8 zf[2];
            #pragma unroll
            for (int m = 0; m < 2; ++m) {
                const int r = m * 16 + mrow;
                const int byte = r * 512 + (((k0 + mq * 8) * 2) ^ ((r & 7) << 4));
                zf[m] = *(const half8*)((const char*)Af + byte);
            }
            half8 bb = *(const half8*)(wb + k0);
            #pragma unroll
            for (int m = 0; m < 2; ++m)
                acc[m] = __builtin_amdgcn_mfma_f32_16x16x32_f16(zf[m], bb, acc[m], 0, 0, 0);
        }
        const int col = w * 16 + mrow;
        const float bv = fc3b[col];
        #pragma unroll
        for (int m = 0; m < 2; ++m)
            #pragma unroll
            for (int reg = 0; reg < 4; ++reg) {
                const int grow = m0 + m * 16 + mq * 4 + reg;
                const int t = grow >> 10, bn = grow & 1023, b = bn >> 6, n = bn & 63;
                out[(((size_t)b * kTS + t) * kN + n) * kDout + col] = acc[m][reg] + bv;
            }
    }
    #undef LAYER
}

extern "C" void kernel_launch(void* const* d_in, const int* in_sizes, int n_in,
                              void* d_out, int out_size, void* d_ws, size_t ws_size,
                              hipStream_t stream) {
    const float* inputs    = (const float*)d_in[0];
    const float* rel_rec   = (const float*)d_in[1];
    const float* rel_send  = (const float*)d_in[2];
    const float* rel_types = (const float*)d_in[3];
    const float* W1  = (const float*)d_in[4];  const float* b1  = (const float*)d_in[5];
    const float* W2  = (const float*)d_in[6];  const float* b2  = (const float*)d_in[7];
    const float* Wir = (const float*)d_in[8];  const float* bir = (const float*)d_in[9];
    const float* Whr = (const float*)d_in[10]; const float* bhr = (const float*)d_in[11];
    const float* Wii = (const float*)d_in[12]; const float* bii = (const float*)d_in[13];
    const float* Whi = (const float*)d_in[14]; const float* bhi = (const float*)d_in[15];
    const float* Win = (const float*)d_in[16]; const float* bin_ = (const float*)d_in[17];
    const float* Whn = (const float*)d_in[18]; const float* bhn = (const float*)d_in[19];
    const float* fc1w = (const float*)d_in[20]; const float* fc1b = (const float*)d_in[21];
    const float* fc2w = (const float*)d_in[22]; const float* fc2b = (const float*)d_in[23];
    const float* fc3w = (const float*)d_in[24]; const float* fc3b = (const float*)d_in[25];
    float* out = (float*)d_out;

    char* w = (char*)d_ws;
    auto take = [&](size_t bytes) { char* p = w; w += (bytes + 255) & ~(size_t)255; return p; };
    int* edge_at = (int*)take(kN * kN * 4);
    float* ts = (float*)take(kB * kE * 4);
    unsigned short* W2f = (unsigned short*)take(kH * kH * 2);
    unsigned short* Wri = (unsigned short*)take(512 * 320 * 2);
    unsigned short* Wnh = (unsigned short*)take(kH * kH * 2);
    unsigned short* Wnx = (unsigned short*)take(kH * kDin * 2);
    unsigned short* Wuv = (unsigned short*)take(512 * 256 * 2);
    unsigned short* F1 = (unsigned short*)take(kH * kH * 2);
    unsigned short* F2 = (unsigned short*)take(kH * kH * 2);
    unsigned short* F3 = (unsigned short*)take(kDout * kH * 2);
    float* bri = (float*)take(512 * 4);
    float* U = (float*)take((size_t)kBN * kH * 4);
    float* V = (float*)take((size_t)kBN * kH * 4);
    float* agg = (float*)take((size_t)kBN * kH * 4);
    float* hh = (float*)w;   // (kTS+1) * kBN * kH floats (~42 MiB)

    hipMemsetAsync(edge_at, 0xFF, kN * kN * 4, stream);
    setup_kernel<<<640, 256, 0, stream>>>(
        rel_rec, rel_send, rel_types, W2, Whr, Whi, Whn, Wir, Wii, Win, W1,
        bir, bhr, bii, bhi, fc1w, fc2w, fc3w,
        edge_at, ts, W2f, Wri, Wnh, Wnx, Wuv, F1, F2, F3, bri);
    hipMemsetAsync(U, 0, (size_t)kBN * kH * 4, stream);
    hipMemsetAsync(V, 0, (size_t)kBN * kH * 4, stream);
    hipMemsetAsync(hh, 0, (size_t)kBN * kH * 4, stream);   // h_0 = 0

    FParams fp;
    fp.inputs = inputs; fp.b1 = b1; fp.b2 = b2; fp.ts = ts; fp.edge_at = edge_at;
    fp.W2f = W2f; fp.Wri = Wri; fp.Wnh = Wnh; fp.Wnx = Wnx; fp.Wuv = Wuv;
    fp.bri = bri; fp.bhn = bhn; fp.bin_ = bin_;
    fp.U = U; fp.V = V; fp.agg = agg; fp.hh = hh;

    void* args[] = {(void*)&fp};
    hipError_t err = hipLaunchCooperativeKernel(
        (const void*)fused_kernel, dim3(512), dim3(512), args, 0, stream);
    if (err != hipSuccess) {
        // deterministic fallback: same phases as separate per-step launches
        for (int t = 0; t < kTS; ++t) {
            edge_step_kernel<<<512, 512, 0, stream>>>(fp);
            gru_step_kernel<<<64, 512, 0, stream>>>(fp, t);
        }
    }

    out_kernel<<<kTS * kBN / 32, 256, 0, stream>>>(
        hh + (size_t)kBN * kH, F1, F2, F3, fc1b, fc2b, fc3b, out);
}

// Round 8
// 2077.581 us; speedup vs baseline: 3.1872x; 3.1872x over previous
//
#include <hip/hip_runtime.h>
#include <math.h>

// GRUDecoder (NRI decoder) on MI355X — round 8: register-hoisted weight loads.
// Back to r6's per-step structure (r7 coop fusion regressed 3x: grid.sync cost
// + L2 writeback). r4->r6 scaling showed time ~ #weight-loads (serialized L2
// latency, VGPR-starved). Fix: hoist ALL B-fragments of each K-loop into VGPRs
// up front (one vmcnt stall), launch_bounds(...,2) to allow ~256 VGPRs.
// Math identical to r6 (passed, absmax 4.39e-3).

namespace {
constexpr int kB = 16, kT = 40, kTS = 39, kN = 64, kDin = 64, kH = 256;
constexpr int kE = kN * (kN - 1);   // 4032
constexpr int kBN = kB * kN;        // 1024
constexpr int kDout = 64;
}

typedef _Float16 half8 __attribute__((ext_vector_type(8)));
typedef float f32x4 __attribute__((ext_vector_type(4)));

__device__ __forceinline__ float sigm(float x) { return 1.f / (1.f + expf(-x)); }

__device__ __forceinline__ unsigned short f2h(float x) {
    _Float16 h = (_Float16)x;          // v_cvt_f16_f32, RNE
    return __builtin_bit_cast(unsigned short, h);
}

__device__ __forceinline__ uint4 pack8h(const float* x) {
    unsigned us[8];
    #pragma unroll
    for (int q = 0; q < 8; ++q) us[q] = f2h(x[q]);
    uint4 p;
    p.x = us[0] | (us[1] << 16); p.y = us[2] | (us[3] << 16);
    p.z = us[4] | (us[5] << 16); p.w = us[6] | (us[7] << 16);
    return p;
}

// ---------------- setup: edge table, type sums, all weights -> fp16 ---------
__global__ void setup_kernel(
    const float* __restrict__ rel_rec, const float* __restrict__ rel_send,
    const float* __restrict__ rel_types, const float* __restrict__ W2,
    const float* __restrict__ Whr, const float* __restrict__ Whi,
    const float* __restrict__ Whn, const float* __restrict__ Wir,
    const float* __restrict__ Wii, const float* __restrict__ Win,
    const float* __restrict__ W1,
    const float* __restrict__ bir, const float* __restrict__ bhr,
    const float* __restrict__ bii, const float* __restrict__ bhi,
    const float* __restrict__ fc1w, const float* __restrict__ fc2w,
    const float* __restrict__ fc3w,
    int* __restrict__ edge_at, float* __restrict__ ts,
    unsigned short* __restrict__ W2f,
    unsigned short* __restrict__ Wri,
    unsigned short* __restrict__ Wnh,
    unsigned short* __restrict__ Wnx,
    unsigned short* __restrict__ Wuv,
    unsigned short* __restrict__ F1, unsigned short* __restrict__ F2,
    unsigned short* __restrict__ F3,
    float* __restrict__ bri) {
    int idx = blockIdx.x * 256 + threadIdx.x;
    if (idx < kE) {
        int si = 0, ri = 0;
        for (int n = 0; n < kN; ++n) {
            if (rel_send[idx * kN + n] > 0.5f) si = n;
            if (rel_rec[idx * kN + n] > 0.5f) ri = n;
        }
        edge_at[ri * kN + si] = idx;
    }
    if (idx < kB * kE) ts[idx] = rel_types[2 * idx] + rel_types[2 * idx + 1];
    if (idx < kH * kH) {
        W2f[idx] = f2h(W2[idx]);
        Wnh[idx] = f2h(Whn[idx]);
        F1[idx] = f2h(fc1w[idx]);
        F2[idx] = f2h(fc2w[idx]);
    }
    if (idx < 512 * 320) {  // Wri = [[Whr|Wir],[Whi|Wii]]  rows x K=320
        int row = idx / 320, k = idx - row * 320;
        float v;
        if (row < 256) v = (k < kH) ? Whr[row * kH + k] : Wir[row * kDin + k - kH];
        else { int o = row - 256; v = (k < kH) ? Whi[o * kH + k] : Wii[o * kDin + k - kH]; }
        Wri[idx] = f2h(v);
    }
    if (idx < kH * kDin) Wnx[idx] = f2h(Win[idx]);
    if (idx < 512 * 256) {  // Wuv: row<256 -> U (W1 cols 0..255), else V
        int row = idx >> 8, k = idx & 255;
        float v = (row < 256) ? W1[row * 512 + k] : W1[(row - 256) * 512 + 256 + k];
        Wuv[idx] = f2h(v);
    }
    if (idx < kDout * kH) F3[idx] = f2h(fc3w[idx]);
    if (idx < 256) bri[idx] = bir[idx] + bhr[idx];
    else if (idx < 512) bri[idx] = bii[idx - 256] + bhi[idx - 256];
}

// ---------------- per-step: edge messages + aggregation (fp16 MFMA) --------
// One block per (b, receiver j). 256 thr = 4 waves. All 32 W2 fragments
// hoisted to VGPRs before the MFMA loop (one latency stall, not eight).
__global__ __launch_bounds__(256, 2)
void edge_kernel(const float* __restrict__ U, const float* __restrict__ V,
                 const unsigned short* __restrict__ W2f,
                 const float* __restrict__ b1, const float* __restrict__ b2,
                 const float* __restrict__ ts, const int* __restrict__ edge_at,
                 float* __restrict__ agg) {
    __shared__ __align__(16) unsigned short h1[kN * kH];  // 32 KiB, swizzled
    __shared__ float vjb[kH];
    __shared__ float tss[kN];
    const int blk = blockIdx.x, b = blk >> 6, j = blk & 63;
    const int tid = threadIdx.x;
    const int lane = tid & 63, w = tid >> 6;
    const int mrow = lane & 15, mq = lane >> 4;

    if (tid < kN) {
        int e = edge_at[j * kN + tid];
        tss[tid] = (e < 0) ? 0.f : ts[b * kE + e];
    }
    vjb[tid] = V[(size_t)(b * kN + j) * kH + tid] + b1[tid];

    // hoist ALL W2 fragments for this wave's 64 cols (32 x 16B = 128 VGPR)
    const unsigned short* Wp = W2f + (size_t)(w * 64 + mrow) * kH + mq * 8;
    half8 bb[8][4];
    #pragma unroll
    for (int kt = 0; kt < 8; ++kt)
        #pragma unroll
        for (int nf = 0; nf < 4; ++nf)
            bb[kt][nf] = *(const half8*)(Wp + nf * 16 * kH + kt * 32);

    __syncthreads();

    // ---- build h1 = relu(U_i + vjb) as fp16, swizzle byte ^= (row&7)<<4
    {
        const int o = tid & 31, i0 = tid >> 5;   // k-octet o, starting row
        const int k0 = o * 8;
        const float4 vj0 = *(const float4*)&vjb[k0];
        const float4 vj1 = *(const float4*)&vjb[k0 + 4];
        #pragma unroll
        for (int p = 0; p < 8; ++p) {
            const int i = i0 + 8 * p;
            const float4* up = (const float4*)(U + (size_t)(b * kN + i) * kH + k0);
            float4 f0 = up[0], f1 = up[1];
            float x[8] = {f0.x + vj0.x, f0.y + vj0.y, f0.z + vj0.z, f0.w + vj0.w,
                          f1.x + vj1.x, f1.y + vj1.y, f1.z + vj1.z, f1.w + vj1.w};
            #pragma unroll
            for (int q = 0; q < 8; ++q) x[q] = (i == j) ? 0.f : fmaxf(x[q], 0.f);
            const int byte = i * 512 + ((k0 * 2) ^ ((i & 7) << 4));
            *(uint4*)((char*)h1 + byte) = pack8h(x);
        }
    }
    __syncthreads();

    // ---- MFMA: out[i][col] = sum_k h1[i][k] * W2[col][k]
    f32x4 acc[4][4];
    #pragma unroll
    for (int mf = 0; mf < 4; ++mf)
        #pragma unroll
        for (int nf = 0; nf < 4; ++nf) acc[mf][nf] = (f32x4){0.f, 0.f, 0.f, 0.f};

    #pragma unroll
    for (int kt = 0; kt < 8; ++kt) {
        const int k0 = kt * 32;
        half8 a[4];
        #pragma unroll
        for (int mf = 0; mf < 4; ++mf) {
            const int r = mf * 16 + mrow;
            const int byte = r * 512 + (((k0 + mq * 8) * 2) ^ ((r & 7) << 4));
            a[mf] = *(const half8*)((const char*)h1 + byte);
        }
        #pragma unroll
        for (int mf = 0; mf < 4; ++mf)
            #pragma unroll
            for (int nf = 0; nf < 4; ++nf)
                acc[mf][nf] = __builtin_amdgcn_mfma_f32_16x16x32_f16(
                    a[mf], bb[kt][nf], acc[mf][nf], 0, 0, 0);
    }

    // ---- epilogue: relu(+b2), ts-weight, reduce over senders (M)
    float tsr[16];
    #pragma unroll
    for (int mf = 0; mf < 4; ++mf)
        #pragma unroll
        for (int r = 0; r < 4; ++r)
            tsr[mf * 4 + r] = tss[mf * 16 + mq * 4 + r];   // D row = (lane>>4)*4+r
    #pragma unroll
    for (int nf = 0; nf < 4; ++nf) {
        const int col = w * 64 + nf * 16 + mrow;
        const float bv = b2[col];
        float s = 0.f;
        #pragma unroll
        for (int mf = 0; mf < 4; ++mf)
            #pragma unroll
            for (int r = 0; r < 4; ++r)
                s += tsr[mf * 4 + r] * fmaxf(acc[mf][nf][r] + bv, 0.f);
        s += __shfl_xor(s, 16);
        s += __shfl_xor(s, 32);
        if (lane < 16) agg[(size_t)(b * kN + j) * kH + col] = s;
    }
}

// ---------------- per-step: GRU gates + hnew + U,V (fp16 MFMA) -------------
// 64 blocks x 512 thr (8 waves). Per-nf weight fragments hoisted to VGPRs.
__global__ __launch_bounds__(512, 2)
void gru_kernel(const float* __restrict__ hprev, const float* __restrict__ agg,
                const float* __restrict__ inputs, int t,
                const unsigned short* __restrict__ Wri,
                const unsigned short* __restrict__ Wnh,
                const unsigned short* __restrict__ Wnx,
                const unsigned short* __restrict__ Wuv,
                const float* __restrict__ bri, const float* __restrict__ bhn,
                const float* __restrict__ bin_,
                float* __restrict__ hnew, float* __restrict__ Uo,
                float* __restrict__ Vo) {
    __shared__ __align__(16) unsigned short Zf[16 * 320];  // 10 KiB
    __shared__ __align__(16) unsigned short Hf[16 * 256];  // 8 KiB
    const int m0 = blockIdx.x * 16;
    const int tid = threadIdx.x;

    // ---- stage Z = [agg | x]: 16 rows x 40 octets, swizzled rows of 640 B
    for (int c = tid; c < 16 * 40; c += 512) {
        const int r = c / 40, g = c - r * 40;
        float x[8];
        if (g < 32) {
            const float* ap = agg + (size_t)(m0 + r) * kH + g * 8;
            *(float4*)&x[0] = ((const float4*)ap)[0];
            *(float4*)&x[4] = ((const float4*)ap)[1];
        } else {
            const int grow = m0 + r, b = grow >> 6, n = grow & 63;
            const float* xp = inputs + ((size_t)(b * kT + t) * kN + n) * kDin + (g - 32) * 8;
            *(float4*)&x[0] = ((const float4*)xp)[0];
            *(float4*)&x[4] = ((const float4*)xp)[1];
        }
        const int byte = r * 640 + ((g ^ (r & 7)) << 4);
        *(uint4*)((char*)Zf + byte) = pack8h(x);
    }
    __syncthreads();

    const int lane = tid & 63, w = tid >> 6;   // 8 waves
    const int mrow = lane & 15, mq = lane >> 4;

    // ---- GEMM1: 2 nf per wave (8 waves x 32 cols = 256)
    #pragma unroll
    for (int nf = 0; nf < 2; ++nf) {
        const int col = w * 32 + nf * 16 + mrow;
        const unsigned short* WR = Wri + (size_t)col * 320 + mq * 8;
        const unsigned short* WI = Wri + (size_t)(256 + col) * 320 + mq * 8;
        const unsigned short* WNh = Wnh + (size_t)col * kH + mq * 8;
        const unsigned short* WNx = Wnx + (size_t)col * kDin + mq * 8;

        // hoist all 30 weight fragments (120 VGPR)
        half8 rwa[10][3];
        #pragma unroll
        for (int kt = 0; kt < 10; ++kt) {
            rwa[kt][0] = *(const half8*)(WR + kt * 32);
            rwa[kt][1] = *(const half8*)(WI + kt * 32);
            if (kt < 8) rwa[kt][2] = *(const half8*)(WNh + kt * 32);
            else        rwa[kt][2] = *(const half8*)(WNx + (kt * 32 - 256));
        }

        f32x4 aR = {0.f,0.f,0.f,0.f}, aI = {0.f,0.f,0.f,0.f};
        f32x4 aNH = {0.f,0.f,0.f,0.f}, aNX = {0.f,0.f,0.f,0.f};
        #pragma unroll
        for (int kt = 0; kt < 10; ++kt) {
            const int g = kt * 4 + mq;
            const int byte = mrow * 640 + ((g ^ (mrow & 7)) << 4);
            half8 zf = *(const half8*)((const char*)Zf + byte);
            aR = __builtin_amdgcn_mfma_f32_16x16x32_f16(zf, rwa[kt][0], aR, 0, 0, 0);
            aI = __builtin_amdgcn_mfma_f32_16x16x32_f16(zf, rwa[kt][1], aI, 0, 0, 0);
            if (kt < 8) aNH = __builtin_amdgcn_mfma_f32_16x16x32_f16(zf, rwa[kt][2], aNH, 0, 0, 0);
            else        aNX = __builtin_amdgcn_mfma_f32_16x16x32_f16(zf, rwa[kt][2], aNX, 0, 0, 0);
        }

        const float brv = bri[col], biv = bri[256 + col];
        const float bhnv = bhn[col], binv = bin_[col];
        #pragma unroll
        for (int reg = 0; reg < 4; ++reg) {
            const int lr = mq * 4 + reg;
            const int grow = m0 + lr;
            float rg = sigm(aR[reg] + brv);
            float ig = sigm(aI[reg] + biv);
            float ng = tanhf(aNX[reg] + binv + rg * (aNH[reg] + bhnv));
            float h2 = (1.f - ig) * ng + ig * hprev[(size_t)grow * kH + col];
            hnew[(size_t)grow * kH + col] = h2;
            const int byte = lr * 512 + (((col >> 3) ^ (lr & 7)) << 4) + (col & 7) * 2;
            *(unsigned short*)((char*)Hf + byte) = f2h(h2);
        }
    }
    __syncthreads();

    // ---- GEMM2: 4 nf per wave (8 waves x 64 cols = 512) -> U,V
    #pragma unroll
    for (int nf = 0; nf < 4; ++nf) {
        const int col = w * 64 + nf * 16 + mrow;
        const unsigned short* Wp = Wuv + (size_t)col * kH + mq * 8;
        half8 rwa[8];
        #pragma unroll
        for (int kt = 0; kt < 8; ++kt) rwa[kt] = *(const half8*)(Wp + kt * 32);
        f32x4 aUV = {0.f, 0.f, 0.f, 0.f};
        #pragma unroll
        for (int kt = 0; kt < 8; ++kt) {
            const int g = kt * 4 + mq;
            const int byte = mrow * 512 + ((g ^ (mrow & 7)) << 4);
            half8 zf = *(const half8*)((const char*)Hf + byte);
            aUV = __builtin_amdgcn_mfma_f32_16x16x32_f16(zf, rwa[kt], aUV, 0, 0, 0);
        }
        #pragma unroll
        for (int reg = 0; reg < 4; ++reg) {
            const int grow = m0 + mq * 4 + reg;
            const float v = aUV[reg];
            if (col < 256) Uo[(size_t)grow * kH + col] = v;
            else Vo[(size_t)grow * kH + col - 256] = v;
        }
    }
}

// ---------------- batched output MLP (fp16 MFMA), hoisted weights ----------
__global__ __launch_bounds__(256, 2)
void out_kernel(const float* __restrict__ hist,
                const unsigned short* __restrict__ F1,
                const unsigned short* __restrict__ F2,
                const unsigned short* __restrict__ F3,
                const float* __restrict__ fc1b, const float* __restrict__ fc2b,
                const float* __restrict__ fc3b, float* __restrict__ out) {
    __shared__ __align__(16) unsigned short Af[32 * 256];  // 16 KiB
    __shared__ __align__(16) unsigned short Bf[32 * 256];  // 16 KiB
    const int m0 = blockIdx.x * 32;
    const int tid = threadIdx.x;

    #pragma unroll
    for (int it = 0; it < 4; ++it) {
        const int c = tid + it * 256;
        const int r = c >> 5, o = c & 31;
        const float* ap = hist + (size_t)(m0 + r) * kH + o * 8;
        float x[8];
        *(float4*)&x[0] = ((const float4*)ap)[0];
        *(float4*)&x[4] = ((const float4*)ap)[1];
        const int byte = r * 512 + ((o << 4) ^ ((r & 7) << 4));
        *(uint4*)((char*)Af + byte) = pack8h(x);
    }
    __syncthreads();

    const int lane = tid & 63, w = tid >> 6;
    const int mrow = lane & 15, mq = lane >> 4;

    #define LAYER(SRC, WW, BIAS, DST)                                           \
    {                                                                           \
        const unsigned short* wb = WW + (size_t)(w * 64 + mrow) * kH + mq * 8;  \
        half8 wall[8][4];                                                       \
        _Pragma("unroll")                                                       \
        for (int kt = 0; kt < 8; ++kt)                                          \
            _Pragma("unroll")                                                   \
            for (int nf = 0; nf < 4; ++nf)                                      \
                wall[kt][nf] = *(const half8*)(wb + nf * 16 * kH + kt * 32);    \
        f32x4 acc[2][4];                                                        \
        _Pragma("unroll")                                                       \
        for (int m = 0; m < 2; ++m)                                             \
            _Pragma("unroll")                                                   \
            for (int nf = 0; nf < 4; ++nf) acc[m][nf] = (f32x4){0.f,0.f,0.f,0.f};\
        _Pragma("unroll")                                                       \
        for (int kt = 0; kt < 8; ++kt) {                                        \
            const int k0 = kt * 32;                                             \
            half8 zf[2];                                                        \
            _Pragma("unroll")                                                   \
            for (int m = 0; m < 2; ++m) {                                       \
                const int r = m * 16 + mrow;                                    \
                const int byte = r * 512 + (((k0 + mq * 8) * 2) ^ ((r & 7) << 4)); \
                zf[m] = *(const half8*)((const char*)SRC + byte);               \
            }                                                                   \
            _Pragma("unroll")                                                   \
            for (int m = 0; m < 2; ++m)                                         \
                _Pragma("unroll")                                               \
                for (int nf = 0; nf < 4; ++nf)                                  \
                    acc[m][nf] = __builtin_amdgcn_mfma_f32_16x16x32_f16(        \
                        zf[m], wall[kt][nf], acc[m][nf], 0, 0, 0);              \
        }                                                                       \
        _Pragma("unroll")                                                       \
        for (int m = 0; m < 2; ++m)                                             \
            _Pragma("unroll")                                                   \
            for (int nf = 0; nf < 4; ++nf) {                                    \
                const int col = w * 64 + nf * 16 + mrow;                        \
                const float bv = BIAS[col];                                     \
                _Pragma("unroll")                                               \
                for (int reg = 0; reg < 4; ++reg) {                             \
                    const int lr = m * 16 + mq * 4 + reg;                       \
                    float v = fmaxf(acc[m][nf][reg] + bv, 0.f);                 \
                    const int byte = lr * 512 + (((col >> 3) ^ (lr & 7)) << 4) + (col & 7) * 2; \
                    *(unsigned short*)((char*)DST + byte) = f2h(v);             \
                }                                                               \
            }                                                                   \
        __syncthreads();                                                        \
    }

    LAYER(Af, F1, fc1b, Bf)
    LAYER(Bf, F2, fc2b, Af)

    // fc3: N=64, per wave 1 frag of 16 cols
    {
        const int row = w * 16 + mrow;
        const unsigned short* wb = F3 + (size_t)row * kH + mq * 8;
        half8 wall[8];
        #pragma unroll
        for (int kt = 0; kt < 8; ++kt) wall[kt] = *(const half8*)(wb + kt * 32);
        f32x4 acc[2];
        acc[0] = (f32x4){0.f, 0.f, 0.f, 0.f};
        acc[1] = (f32x4){0.f, 0.f, 0.f, 0.f};
        #pragma unroll
        for (int kt = 0; kt < 8; ++kt) {
            const int k0 = kt * 32;
            half8 zf[2];
            #pragma unroll
            for (int m = 0; m < 2; ++m) {
                const int r = m * 16 + mrow;
                const int byte = r * 512 + (((k0 + mq * 8) * 2) ^ ((r & 7) << 4));
                zf[m] = *(const half8*)((const char*)Af + byte);
            }
            #pragma unroll
            for (int m = 0; m < 2; ++m)
                acc[m] = __builtin_amdgcn_mfma_f32_16x16x32_f16(zf[m], wall[kt], acc[m], 0, 0, 0);
        }
        const int col = w * 16 + mrow;
        const float bv = fc3b[col];
        #pragma unroll
        for (int m = 0; m < 2; ++m)
            #pragma unroll
            for (int reg = 0; reg < 4; ++reg) {
                const int grow = m0 + m * 16 + mq * 4 + reg;
                const int t = grow >> 10, bn = grow & 1023, b = bn >> 6, n = bn & 63;
                out[(((size_t)b * kTS + t) * kN + n) * kDout + col] = acc[m][reg] + bv;
            }
    }
    #undef LAYER
}

extern "C" void kernel_launch(void* const* d_in, const int* in_sizes, int n_in,
                              void* d_out, int out_size, void* d_ws, size_t ws_size,
                              hipStream_t stream) {
    const float* inputs    = (const float*)d_in[0];
    const float* rel_rec   = (const float*)d_in[1];
    const float* rel_send  = (const float*)d_in[2];
    const float* rel_types = (const float*)d_in[3];
    const float* W1  = (const float*)d_in[4];  const float* b1  = (const float*)d_in[5];
    const float* W2  = (const float*)d_in[6];  const float* b2  = (const float*)d_in[7];
    const float* Wir = (const float*)d_in[8];  const float* bir = (const float*)d_in[9];
    const float* Whr = (const float*)d_in[10]; const float* bhr = (const float*)d_in[11];
    const float* Wii = (const float*)d_in[12]; const float* bii = (const float*)d_in[13];
    const float* Whi = (const float*)d_in[14]; const float* bhi = (const float*)d_in[15];
    const float* Win = (const float*)d_in[16]; const float* bin_ = (const float*)d_in[17];
    const float* Whn = (const float*)d_in[18]; const float* bhn = (const float*)d_in[19];
    const float* fc1w = (const float*)d_in[20]; const float* fc1b = (const float*)d_in[21];
    const float* fc2w = (const float*)d_in[22]; const float* fc2b = (const float*)d_in[23];
    const float* fc3w = (const float*)d_in[24]; const float* fc3b = (const float*)d_in[25];
    float* out = (float*)d_out;

    char* w = (char*)d_ws;
    auto take = [&](size_t bytes) { char* p = w; w += (bytes + 255) & ~(size_t)255; return p; };
    int* edge_at = (int*)take(kN * kN * 4);
    float* ts = (float*)take(kB * kE * 4);
    unsigned short* W2f = (unsigned short*)take(kH * kH * 2);
    unsigned short* Wri = (unsigned short*)take(512 * 320 * 2);
    unsigned short* Wnh = (unsigned short*)take(kH * kH * 2);
    unsigned short* Wnx = (unsigned short*)take(kH * kDin * 2);
    unsigned short* Wuv = (unsigned short*)take(512 * 256 * 2);
    unsigned short* F1 = (unsigned short*)take(kH * kH * 2);
    unsigned short* F2 = (unsigned short*)take(kH * kH * 2);
    unsigned short* F3 = (unsigned short*)take(kDout * kH * 2);
    float* bri = (float*)take(512 * 4);
    float* U = (float*)take((size_t)kBN * kH * 4);
    float* V = (float*)take((size_t)kBN * kH * 4);
    float* agg = (float*)take((size_t)kBN * kH * 4);
    float* hh = (float*)w;   // (kTS+1) * kBN * kH floats (~42 MiB)

    hipMemsetAsync(edge_at, 0xFF, kN * kN * 4, stream);
    setup_kernel<<<640, 256, 0, stream>>>(
        rel_rec, rel_send, rel_types, W2, Whr, Whi, Whn, Wir, Wii, Win, W1,
        bir, bhr, bii, bhi, fc1w, fc2w, fc3w,
        edge_at, ts, W2f, Wri, Wnh, Wnx, Wuv, F1, F2, F3, bri);
    hipMemsetAsync(U, 0, (size_t)kBN * kH * 4, stream);
    hipMemsetAsync(V, 0, (size_t)kBN * kH * 4, stream);
    hipMemsetAsync(hh, 0, (size_t)kBN * kH * 4, stream);   // h_0 = 0

    for (int t = 0; t < kTS; ++t) {
        edge_kernel<<<kBN, 256, 0, stream>>>(U, V, W2f, b1, b2, ts, edge_at, agg);
        gru_kernel<<<kBN / 16, 512, 0, stream>>>(
            hh + (size_t)t * kBN * kH, agg, inputs, t,
            Wri, Wnh, Wnx, Wuv, bri, bhn, bin_,
            hh + (size_t)(t + 1) * kBN * kH, U, V);
    }
    out_kernel<<<kTS * kBN / 32, 256, 0, stream>>>(
        hh + (size_t)kBN * kH, F1, F2, F3, fc1b, fc2b, fc3b, out);
}

// Round 9
// 2061.724 us; speedup vs baseline: 3.2117x; 1.0077x over previous
//
#include <hip/hip_runtime.h>
#include <math.h>

// GRUDecoder (NRI decoder) on MI355X — round 9.
// r8 lesson: compiler sank the hoisted weight loads (VGPR stayed 60). Fixes:
//  - sched_barrier(0) after each weight hoist to force the load cluster (MLP)
//  - gru: 256 blocks x 4 rows (full CU coverage; was 64 blocks = 1/4 CUs)
//  - out: 64 rows/block (2x weight amortization)
// Math identical to r6/r8 (passed, absmax 4.394e-3).

namespace {
constexpr int kB = 16, kT = 40, kTS = 39, kN = 64, kDin = 64, kH = 256;
constexpr int kE = kN * (kN - 1);   // 4032
constexpr int kBN = kB * kN;        // 1024
constexpr int kDout = 64;
}

typedef _Float16 half8 __attribute__((ext_vector_type(8)));
typedef float f32x4 __attribute__((ext_vector_type(4)));

__device__ __forceinline__ float sigm(float x) { return 1.f / (1.f + expf(-x)); }

__device__ __forceinline__ unsigned short f2h(float x) {
    _Float16 h = (_Float16)x;          // v_cvt_f16_f32, RNE
    return __builtin_bit_cast(unsigned short, h);
}

__device__ __forceinline__ uint4 pack8h(const float* x) {
    unsigned us[8];
    #pragma unroll
    for (int q = 0; q < 8; ++q) us[q] = f2h(x[q]);
    uint4 p;
    p.x = us[0] | (us[1] << 16); p.y = us[2] | (us[3] << 16);
    p.z = us[4] | (us[5] << 16); p.w = us[6] | (us[7] << 16);
    return p;
}

// ---------------- setup: edge table, type sums, all weights -> fp16 ---------
__global__ void setup_kernel(
    const float* __restrict__ rel_rec, const float* __restrict__ rel_send,
    const float* __restrict__ rel_types, const float* __restrict__ W2,
    const float* __restrict__ Whr, const float* __restrict__ Whi,
    const float* __restrict__ Whn, const float* __restrict__ Wir,
    const float* __restrict__ Wii, const float* __restrict__ Win,
    const float* __restrict__ W1,
    const float* __restrict__ bir, const float* __restrict__ bhr,
    const float* __restrict__ bii, const float* __restrict__ bhi,
    const float* __restrict__ fc1w, const float* __restrict__ fc2w,
    const float* __restrict__ fc3w,
    int* __restrict__ edge_at, float* __restrict__ ts,
    unsigned short* __restrict__ W2f,
    unsigned short* __restrict__ Wri,
    unsigned short* __restrict__ Wnh,
    unsigned short* __restrict__ Wnx,
    unsigned short* __restrict__ Wuv,
    unsigned short* __restrict__ F1, unsigned short* __restrict__ F2,
    unsigned short* __restrict__ F3,
    float* __restrict__ bri) {
    int idx = blockIdx.x * 256 + threadIdx.x;
    if (idx < kE) {
        int si = 0, ri = 0;
        for (int n = 0; n < kN; ++n) {
            if (rel_send[idx * kN + n] > 0.5f) si = n;
            if (rel_rec[idx * kN + n] > 0.5f) ri = n;
        }
        edge_at[ri * kN + si] = idx;
    }
    if (idx < kB * kE) ts[idx] = rel_types[2 * idx] + rel_types[2 * idx + 1];
    if (idx < kH * kH) {
        W2f[idx] = f2h(W2[idx]);
        Wnh[idx] = f2h(Whn[idx]);
        F1[idx] = f2h(fc1w[idx]);
        F2[idx] = f2h(fc2w[idx]);
    }
    if (idx < 512 * 320) {  // Wri = [[Whr|Wir],[Whi|Wii]]  rows x K=320
        int row = idx / 320, k = idx - row * 320;
        float v;
        if (row < 256) v = (k < kH) ? Whr[row * kH + k] : Wir[row * kDin + k - kH];
        else { int o = row - 256; v = (k < kH) ? Whi[o * kH + k] : Wii[o * kDin + k - kH]; }
        Wri[idx] = f2h(v);
    }
    if (idx < kH * kDin) Wnx[idx] = f2h(Win[idx]);
    if (idx < 512 * 256) {  // Wuv: row<256 -> U (W1 cols 0..255), else V
        int row = idx >> 8, k = idx & 255;
        float v = (row < 256) ? W1[row * 512 + k] : W1[(row - 256) * 512 + 256 + k];
        Wuv[idx] = f2h(v);
    }
    if (idx < kDout * kH) F3[idx] = f2h(fc3w[idx]);
    if (idx < 256) bri[idx] = bir[idx] + bhr[idx];
    else if (idx < 512) bri[idx] = bii[idx - 256] + bhi[idx - 256];
}

// ---------------- per-step: edge messages + aggregation (fp16 MFMA) --------
// One block per (b, receiver j). 256 thr = 4 waves. W2 fragments hoisted,
// sched_barrier(0) pins the load cluster ahead of staging -> latency overlap.
__global__ __launch_bounds__(256, 2)
void edge_kernel(const float* __restrict__ U, const float* __restrict__ V,
                 const unsigned short* __restrict__ W2f,
                 const float* __restrict__ b1, const float* __restrict__ b2,
                 const float* __restrict__ ts, const int* __restrict__ edge_at,
                 float* __restrict__ agg) {
    __shared__ __align__(16) unsigned short h1[kN * kH];  // 32 KiB, swizzled
    __shared__ float vjb[kH];
    __shared__ float tss[kN];
    const int blk = blockIdx.x, b = blk >> 6, j = blk & 63;
    const int tid = threadIdx.x;
    const int lane = tid & 63, w = tid >> 6;
    const int mrow = lane & 15, mq = lane >> 4;

    if (tid < kN) {
        int e = edge_at[j * kN + tid];
        tss[tid] = (e < 0) ? 0.f : ts[b * kE + e];
    }
    vjb[tid] = V[(size_t)(b * kN + j) * kH + tid] + b1[tid];

    // hoist ALL W2 fragments for this wave's 64 cols (32 x 16B = 128 VGPR)
    const unsigned short* Wp = W2f + (size_t)(w * 64 + mrow) * kH + mq * 8;
    half8 bb[8][4];
    #pragma unroll
    for (int kt = 0; kt < 8; ++kt)
        #pragma unroll
        for (int nf = 0; nf < 4; ++nf)
            bb[kt][nf] = *(const half8*)(Wp + nf * 16 * kH + kt * 32);
    __builtin_amdgcn_sched_barrier(0);   // keep the load cluster HERE

    __syncthreads();

    // ---- build h1 = relu(U_i + vjb) as fp16, swizzle byte ^= (row&7)<<4
    {
        const int o = tid & 31, i0 = tid >> 5;   // k-octet o, starting row
        const int k0 = o * 8;
        const float4 vj0 = *(const float4*)&vjb[k0];
        const float4 vj1 = *(const float4*)&vjb[k0 + 4];
        #pragma unroll
        for (int p = 0; p < 8; ++p) {
            const int i = i0 + 8 * p;
            const float4* up = (const float4*)(U + (size_t)(b * kN + i) * kH + k0);
            float4 f0 = up[0], f1 = up[1];
            float x[8] = {f0.x + vj0.x, f0.y + vj0.y, f0.z + vj0.z, f0.w + vj0.w,
                          f1.x + vj1.x, f1.y + vj1.y, f1.z + vj1.z, f1.w + vj1.w};
            #pragma unroll
            for (int q = 0; q < 8; ++q) x[q] = (i == j) ? 0.f : fmaxf(x[q], 0.f);
            const int byte = i * 512 + ((k0 * 2) ^ ((i & 7) << 4));
            *(uint4*)((char*)h1 + byte) = pack8h(x);
        }
    }
    __syncthreads();

    // ---- MFMA: out[i][col] = sum_k h1[i][k] * W2[col][k]
    f32x4 acc[4][4];
    #pragma unroll
    for (int mf = 0; mf < 4; ++mf)
        #pragma unroll
        for (int nf = 0; nf < 4; ++nf) acc[mf][nf] = (f32x4){0.f, 0.f, 0.f, 0.f};

    #pragma unroll
    for (int kt = 0; kt < 8; ++kt) {
        const int k0 = kt * 32;
        half8 a[4];
        #pragma unroll
        for (int mf = 0; mf < 4; ++mf) {
            const int r = mf * 16 + mrow;
            const int byte = r * 512 + (((k0 + mq * 8) * 2) ^ ((r & 7) << 4));
            a[mf] = *(const half8*)((const char*)h1 + byte);
        }
        #pragma unroll
        for (int mf = 0; mf < 4; ++mf)
            #pragma unroll
            for (int nf = 0; nf < 4; ++nf)
                acc[mf][nf] = __builtin_amdgcn_mfma_f32_16x16x32_f16(
                    a[mf], bb[kt][nf], acc[mf][nf], 0, 0, 0);
    }

    // ---- epilogue: relu(+b2), ts-weight, reduce over senders (M)
    float tsr[16];
    #pragma unroll
    for (int mf = 0; mf < 4; ++mf)
        #pragma unroll
        for (int r = 0; r < 4; ++r)
            tsr[mf * 4 + r] = tss[mf * 16 + mq * 4 + r];   // D row = (lane>>4)*4+r
    #pragma unroll
    for (int nf = 0; nf < 4; ++nf) {
        const int col = w * 64 + nf * 16 + mrow;
        const float bv = b2[col];
        float s = 0.f;
        #pragma unroll
        for (int mf = 0; mf < 4; ++mf)
            #pragma unroll
            for (int r = 0; r < 4; ++r)
                s += tsr[mf * 4 + r] * fmaxf(acc[mf][nf][r] + bv, 0.f);
        s += __shfl_xor(s, 16);
        s += __shfl_xor(s, 32);
        if (lane < 16) agg[(size_t)(b * kN + j) * kH + col] = s;
    }
}

// ---------------- per-step: GRU gates + hnew + U,V (fp16 MFMA) -------------
// 256 blocks x 512 thr (8 waves); block owns 4 rows (M-tile rows 4..15 zero).
__global__ __launch_bounds__(512, 2)
void gru_kernel(const float* __restrict__ hprev, const float* __restrict__ agg,
                const float* __restrict__ inputs, int t,
                const unsigned short* __restrict__ Wri,
                const unsigned short* __restrict__ Wnh,
                const unsigned short* __restrict__ Wnx,
                const unsigned short* __restrict__ Wuv,
                const float* __restrict__ bri, const float* __restrict__ bhn,
                const float* __restrict__ bin_,
                float* __restrict__ hnew, float* __restrict__ Uo,
                float* __restrict__ Vo) {
    __shared__ __align__(16) unsigned short Zf[16 * 320];  // 10 KiB
    __shared__ __align__(16) unsigned short Hf[16 * 256];  // 8 KiB
    const int m0 = blockIdx.x * 4;
    const int tid = threadIdx.x;

    // ---- stage Z = [agg | x] rows 0..3; zero rows 4..15 (Zf and Hf)
    {
        const uint4 z4 = {0u, 0u, 0u, 0u};
        for (int c = tid; c < 4 * 40; c += 512) {
            const int r = c / 40, g = c - r * 40;
            float x[8];
            if (g < 32) {
                const float* ap = agg + (size_t)(m0 + r) * kH + g * 8;
                *(float4*)&x[0] = ((const float4*)ap)[0];
                *(float4*)&x[4] = ((const float4*)ap)[1];
            } else {
                const int grow = m0 + r, b = grow >> 6, n = grow & 63;
                const float* xp = inputs + ((size_t)(b * kT + t) * kN + n) * kDin + (g - 32) * 8;
                *(float4*)&x[0] = ((const float4*)xp)[0];
                *(float4*)&x[4] = ((const float4*)xp)[1];
            }
            const int byte = r * 640 + ((g ^ (r & 7)) << 4);
            *(uint4*)((char*)Zf + byte) = pack8h(x);
        }
        for (int c = tid; c < 12 * 40; c += 512) {
            const int r = 4 + c / 40, g = c - (c / 40) * 40;
            const int byte = r * 640 + ((g ^ (r & 7)) << 4);
            *(uint4*)((char*)Zf + byte) = z4;
        }
        for (int c = tid; c < 12 * 32; c += 512) {
            const int r = 4 + c / 32, g = c & 31;
            const int byte = r * 512 + ((g ^ (r & 7)) << 4);
            *(uint4*)((char*)Hf + byte) = z4;
        }
    }
    __syncthreads();

    const int lane = tid & 63, w = tid >> 6;   // 8 waves
    const int mrow = lane & 15, mq = lane >> 4;

    // ---- GEMM1: 2 nf per wave (8 waves x 32 cols = 256)
    #pragma unroll
    for (int nf = 0; nf < 2; ++nf) {
        const int col = w * 32 + nf * 16 + mrow;
        const unsigned short* WR = Wri + (size_t)col * 320 + mq * 8;
        const unsigned short* WI = Wri + (size_t)(256 + col) * 320 + mq * 8;
        const unsigned short* WNh = Wnh + (size_t)col * kH + mq * 8;
        const unsigned short* WNx = Wnx + (size_t)col * kDin + mq * 8;

        half8 rwa[10][3];
        #pragma unroll
        for (int kt = 0; kt < 10; ++kt) {
            rwa[kt][0] = *(const half8*)(WR + kt * 32);
            rwa[kt][1] = *(const half8*)(WI + kt * 32);
            if (kt < 8) rwa[kt][2] = *(const half8*)(WNh + kt * 32);
            else        rwa[kt][2] = *(const half8*)(WNx + (kt * 32 - 256));
        }
        __builtin_amdgcn_sched_barrier(0);

        f32x4 aR = {0.f,0.f,0.f,0.f}, aI = {0.f,0.f,0.f,0.f};
        f32x4 aNH = {0.f,0.f,0.f,0.f}, aNX = {0.f,0.f,0.f,0.f};
        #pragma unroll
        for (int kt = 0; kt < 10; ++kt) {
            const int g = kt * 4 + mq;
            const int byte = mrow * 640 + ((g ^ (mrow & 7)) << 4);
            half8 zf = *(const half8*)((const char*)Zf + byte);
            aR = __builtin_amdgcn_mfma_f32_16x16x32_f16(zf, rwa[kt][0], aR, 0, 0, 0);
            aI = __builtin_amdgcn_mfma_f32_16x16x32_f16(zf, rwa[kt][1], aI, 0, 0, 0);
            if (kt < 8) aNH = __builtin_amdgcn_mfma_f32_16x16x32_f16(zf, rwa[kt][2], aNH, 0, 0, 0);
            else        aNX = __builtin_amdgcn_mfma_f32_16x16x32_f16(zf, rwa[kt][2], aNX, 0, 0, 0);
        }

        if (mq == 0) {  // only D rows 0..3 are real
            const float brv = bri[col], biv = bri[256 + col];
            const float bhnv = bhn[col], binv = bin_[col];
            #pragma unroll
            for (int reg = 0; reg < 4; ++reg) {
                const int lr = reg;            // mq==0 -> row = reg
                const int grow = m0 + lr;
                float rg = sigm(aR[reg] + brv);
                float ig = sigm(aI[reg] + biv);
                float ng = tanhf(aNX[reg] + binv + rg * (aNH[reg] + bhnv));
                float h2 = (1.f - ig) * ng + ig * hprev[(size_t)grow * kH + col];
                hnew[(size_t)grow * kH + col] = h2;
                const int byte = lr * 512 + (((col >> 3) ^ (lr & 7)) << 4) + (col & 7) * 2;
                *(unsigned short*)((char*)Hf + byte) = f2h(h2);
            }
        }
    }
    __syncthreads();

    // ---- GEMM2: 4 nf per wave (8 waves x 64 cols = 512) -> U,V
    #pragma unroll
    for (int nf = 0; nf < 4; ++nf) {
        const int col = w * 64 + nf * 16 + mrow;
        const unsigned short* Wp = Wuv + (size_t)col * kH + mq * 8;
        half8 rwa[8];
        #pragma unroll
        for (int kt = 0; kt < 8; ++kt) rwa[kt] = *(const half8*)(Wp + kt * 32);
        __builtin_amdgcn_sched_barrier(0);
        f32x4 aUV = {0.f, 0.f, 0.f, 0.f};
        #pragma unroll
        for (int kt = 0; kt < 8; ++kt) {
            const int g = kt * 4 + mq;
            const int byte = mrow * 512 + ((g ^ (mrow & 7)) << 4);
            half8 zf = *(const half8*)((const char*)Hf + byte);
            aUV = __builtin_amdgcn_mfma_f32_16x16x32_f16(zf, rwa[kt], aUV, 0, 0, 0);
        }
        if (mq == 0) {
            #pragma unroll
            for (int reg = 0; reg < 4; ++reg) {
                const int grow = m0 + reg;
                const float v = aUV[reg];
                if (col < 256) Uo[(size_t)grow * kH + col] = v;
                else Vo[(size_t)grow * kH + col - 256] = v;
            }
        }
    }
}

// ---------------- batched output MLP (fp16 MFMA), 64 rows/block -------------
__global__ __launch_bounds__(256, 2)
void out_kernel(const float* __restrict__ hist,
                const unsigned short* __restrict__ F1,
                const unsigned short* __restrict__ F2,
                const unsigned short* __restrict__ F3,
                const float* __restrict__ fc1b, const float* __restrict__ fc2b,
                const float* __restrict__ fc3b, float* __restrict__ out) {
    __shared__ __align__(16) unsigned short Af[64 * 256];  // 32 KiB
    __shared__ __align__(16) unsigned short Bf[64 * 256];  // 32 KiB
    const int m0 = blockIdx.x * 64;
    const int tid = threadIdx.x;
    const int lane = tid & 63, w = tid >> 6;
    const int mrow = lane & 15, mq = lane >> 4;

    #pragma unroll
    for (int it = 0; it < 8; ++it) {
        const int c = tid + it * 256;
        const int r = c >> 5, o = c & 31;
        const float* ap = hist + (size_t)(m0 + r) * kH + o * 8;
        float x[8];
        *(float4*)&x[0] = ((const float4*)ap)[0];
        *(float4*)&x[4] = ((const float4*)ap)[1];
        const int byte = r * 512 + ((o << 4) ^ ((r & 7) << 4));
        *(uint4*)((char*)Af + byte) = pack8h(x);
    }
    __syncthreads();

    #define LAYER(SRC, WW, BIAS, DST)                                           \
    {                                                                           \
        const unsigned short* wb = WW + (size_t)(w * 64 + mrow) * kH + mq * 8;  \
        half8 wall[8][4];                                                       \
        _Pragma("unroll")                                                       \
        for (int kt = 0; kt < 8; ++kt)                                          \
            _Pragma("unroll")                                                   \
            for (int nf = 0; nf < 4; ++nf)                                      \
                wall[kt][nf] = *(const half8*)(wb + nf * 16 * kH + kt * 32);    \
        __builtin_amdgcn_sched_barrier(0);                                      \
        f32x4 acc[4][4];                                                        \
        _Pragma("unroll")                                                       \
        for (int m = 0; m < 4; ++m)                                             \
            _Pragma("unroll")                                                   \
            for (int nf = 0; nf < 4; ++nf) acc[m][nf] = (f32x4){0.f,0.f,0.f,0.f};\
        _Pragma("unroll")                                                       \
        for (int kt = 0; kt < 8; ++kt) {                                        \
            const int k0 = kt * 32;                                             \
            half8 zf[4];                                                        \
            _Pragma("unroll")                                                   \
            for (int m = 0; m < 4; ++m) {                                       \
                const int r = m * 16 + mrow;                                    \
                const int byte = r * 512 + (((k0 + mq * 8) * 2) ^ ((r & 7) << 4)); \
                zf[m] = *(const half8*)((const char*)SRC + byte);               \
            }                                                                   \
            _Pragma("unroll")                                                   \
            for (int m = 0; m < 4; ++m)                                         \
                _Pragma("unroll")                                               \
                for (int nf = 0; nf < 4; ++nf)                                  \
                    acc[m][nf] = __builtin_amdgcn_mfma_f32_16x16x32_f16(        \
                        zf[m], wall[kt][nf], acc[m][nf], 0, 0, 0);              \
        }                                                                       \
        _Pragma("unroll")                                                       \
        for (int m = 0; m < 4; ++m)                                             \
            _Pragma("unroll")                                                   \
            for (int nf = 0; nf < 4; ++nf) {                                    \
                const int col = w * 64 + nf * 16 + mrow;                        \
                const float bv = BIAS[col];                                     \
                _Pragma("unroll")                                               \
                for (int reg = 0; reg < 4; ++reg) {                             \
                    const int lr = m * 16 + mq * 4 + reg;                       \
                    float v = fmaxf(acc[m][nf][reg] + bv, 0.f);                 \
                    const int byte = lr * 512 + (((col >> 3) ^ (lr & 7)) << 4) + (col & 7) * 2; \
                    *(unsigned short*)((char*)DST + byte) = f2h(v);             \
                }                                                               \
            }                                                                   \
        __syncthreads();                                                        \
    }

    LAYER(Af, F1, fc1b, Bf)
    LAYER(Bf, F2, fc2b, Af)

    // fc3: N=64, per wave 1 frag of 16 cols, 4 row tiles
    {
        const int row = w * 16 + mrow;
        const unsigned short* wb = F3 + (size_t)row * kH + mq * 8;
        half8 wall[8];
        #pragma unroll
        for (int kt = 0; kt < 8; ++kt) wall[kt] = *(const half8*)(wb + kt * 32);
        __builtin_amdgcn_sched_barrier(0);
        f32x4 acc[4];
        #pragma unroll
        for (int m = 0; m < 4; ++m) acc[m] = (f32x4){0.f, 0.f, 0.f, 0.f};
        #pragma unroll
        for (int kt = 0; kt < 8; ++kt) {
            const int k0 = kt * 32;
            half8 zf[4];
            #pragma unroll
            for (int m = 0; m < 4; ++m) {
                const int r = m * 16 + mrow;
                const int byte = r * 512 + (((k0 + mq * 8) * 2) ^ ((r & 7) << 4));
                zf[m] = *(const half8*)((const char*)Af + byte);
            }
            #pragma unroll
            for (int m = 0; m < 4; ++m)
                acc[m] = __builtin_amdgcn_mfma_f32_16x16x32_f16(zf[m], wall[kt], acc[m], 0, 0, 0);
        }
        const int col = w * 16 + mrow;
        const float bv = fc3b[col];
        #pragma unroll
        for (int m = 0; m < 4; ++m)
            #pragma unroll
            for (int reg = 0; reg < 4; ++reg) {
                const int grow = m0 + m * 16 + mq * 4 + reg;
                const int t = grow >> 10, bn = grow & 1023, b = bn >> 6, n = bn & 63;
                out[(((size_t)b * kTS + t) * kN + n) * kDout + col] = acc[m][reg] + bv;
            }
    }
    #undef LAYER
}

extern "C" void kernel_launch(void* const* d_in, const int* in_sizes, int n_in,
                              void* d_out, int out_size, void* d_ws, size_t ws_size,
                              hipStream_t stream) {
    const float* inputs    = (const float*)d_in[0];
    const float* rel_rec   = (const float*)d_in[1];
    const float* rel_send  = (const float*)d_in[2];
    const float* rel_types = (const float*)d_in[3];
    const float* W1  = (const float*)d_in[4];  const float* b1  = (const float*)d_in[5];
    const float* W2  = (const float*)d_in[6];  const float* b2  = (const float*)d_in[7];
    const float* Wir = (const float*)d_in[8];  const float* bir = (const float*)d_in[9];
    const float* Whr = (const float*)d_in[10]; const float* bhr = (const float*)d_in[11];
    const float* Wii = (const float*)d_in[12]; const float* bii = (const float*)d_in[13];
    const float* Whi = (const float*)d_in[14]; const float* bhi = (const float*)d_in[15];
    const float* Win = (const float*)d_in[16]; const float* bin_ = (const float*)d_in[17];
    const float* Whn = (const float*)d_in[18]; const float* bhn = (const float*)d_in[19];
    const float* fc1w = (const float*)d_in[20]; const float* fc1b = (const float*)d_in[21];
    const float* fc2w = (const float*)d_in[22]; const float* fc2b = (const float*)d_in[23];
    const float* fc3w = (const float*)d_in[24]; const float* fc3b = (const float*)d_in[25];
    float* out = (float*)d_out;

    char* w = (char*)d_ws;
    auto take = [&](size_t bytes) { char* p = w; w += (bytes + 255) & ~(size_t)255; return p; };
    int* edge_at = (int*)take(kN * kN * 4);
    float* ts = (float*)take(kB * kE * 4);
    unsigned short* W2f = (unsigned short*)take(kH * kH * 2);
    unsigned short* Wri = (unsigned short*)take(512 * 320 * 2);
    unsigned short* Wnh = (unsigned short*)take(kH * kH * 2);
    unsigned short* Wnx = (unsigned short*)take(kH * kDin * 2);
    unsigned short* Wuv = (unsigned short*)take(512 * 256 * 2);
    unsigned short* F1 = (unsigned short*)take(kH * kH * 2);
    unsigned short* F2 = (unsigned short*)take(kH * kH * 2);
    unsigned short* F3 = (unsigned short*)take(kDout * kH * 2);
    float* bri = (float*)take(512 * 4);
    float* U = (float*)take((size_t)kBN * kH * 4);
    float* V = (float*)take((size_t)kBN * kH * 4);
    float* agg = (float*)take((size_t)kBN * kH * 4);
    float* hh = (float*)w;   // (kTS+1) * kBN * kH floats (~42 MiB)

    hipMemsetAsync(edge_at, 0xFF, kN * kN * 4, stream);
    setup_kernel<<<640, 256, 0, stream>>>(
        rel_rec, rel_send, rel_types, W2, Whr, Whi, Whn, Wir, Wii, Win, W1,
        bir, bhr, bii, bhi, fc1w, fc2w, fc3w,
        edge_at, ts, W2f, Wri, Wnh, Wnx, Wuv, F1, F2, F3, bri);
    hipMemsetAsync(U, 0, (size_t)kBN * kH * 4, stream);
    hipMemsetAsync(V, 0, (size_t)kBN * kH * 4, stream);
    hipMemsetAsync(hh, 0, (size_t)kBN * kH * 4, stream);   // h_0 = 0

    for (int t = 0; t < kTS; ++t) {
        edge_kernel<<<kBN, 256, 0, stream>>>(U, V, W2f, b1, b2, ts, edge_at, agg);
        gru_kernel<<<kBN / 4, 512, 0, stream>>>(
            hh + (size_t)t * kBN * kH, agg, inputs, t,
            Wri, Wnh, Wnx, Wuv, bri, bhn, bin_,
            hh + (size_t)(t + 1) * kBN * kH, U, V);
    }
    out_kernel<<<kTS * kBN / 64, 256, 0, stream>>>(
        hh + (size_t)kBN * kH, F1, F2, F3, fc1b, fc2b, fc3b, out);
}

// Round 10
// 1600.984 us; speedup vs baseline: 4.1360x; 1.2878x over previous
//
#include <hip/hip_runtime.h>
#include <math.h>

// GRUDecoder (NRI decoder) on MI355X — round 10: edge+gru fused per step.
// Key dep insight: GRU row (b,n) needs only agg[b,n], produced by edge block
// (b,j=n). Block owns 4 receivers: computes their agg (LDS-only), then their
// GRU gates + hnew + U,V. 39 launches instead of 78 (boundary ~18us each).
// U,V double-buffered across launches (intra-launch read/write race fix).
// MFMA math/accumulation order identical to r6/r9 (absmax 4.394e-3).

namespace {
constexpr int kB = 16, kT = 40, kTS = 39, kN = 64, kDin = 64, kH = 256;
constexpr int kE = kN * (kN - 1);   // 4032
constexpr int kBN = kB * kN;        // 1024
constexpr int kDout = 64;
}

typedef _Float16 half8 __attribute__((ext_vector_type(8)));
typedef float f32x4 __attribute__((ext_vector_type(4)));

__device__ __forceinline__ float sigm(float x) { return 1.f / (1.f + expf(-x)); }

__device__ __forceinline__ unsigned short f2h(float x) {
    _Float16 h = (_Float16)x;          // v_cvt_f16_f32, RNE
    return __builtin_bit_cast(unsigned short, h);
}

__device__ __forceinline__ uint4 pack8h(const float* x) {
    unsigned us[8];
    #pragma unroll
    for (int q = 0; q < 8; ++q) us[q] = f2h(x[q]);
    uint4 p;
    p.x = us[0] | (us[1] << 16); p.y = us[2] | (us[3] << 16);
    p.z = us[4] | (us[5] << 16); p.w = us[6] | (us[7] << 16);
    return p;
}

// ---------------- setup: edge table, type sums, all weights -> fp16 ---------
__global__ void setup_kernel(
    const float* __restrict__ rel_rec, const float* __restrict__ rel_send,
    const float* __restrict__ rel_types, const float* __restrict__ W2,
    const float* __restrict__ Whr, const float* __restrict__ Whi,
    const float* __restrict__ Whn, const float* __restrict__ Wir,
    const float* __restrict__ Wii, const float* __restrict__ Win,
    const float* __restrict__ W1,
    const float* __restrict__ bir, const float* __restrict__ bhr,
    const float* __restrict__ bii, const float* __restrict__ bhi,
    const float* __restrict__ fc1w, const float* __restrict__ fc2w,
    const float* __restrict__ fc3w,
    int* __restrict__ edge_at, float* __restrict__ ts,
    unsigned short* __restrict__ W2f,
    unsigned short* __restrict__ Wri,
    unsigned short* __restrict__ Wnh,
    unsigned short* __restrict__ Wnx,
    unsigned short* __restrict__ Wuv,
    unsigned short* __restrict__ F1, unsigned short* __restrict__ F2,
    unsigned short* __restrict__ F3,
    float* __restrict__ bri) {
    int idx = blockIdx.x * 256 + threadIdx.x;
    if (idx < kE) {
        int si = 0, ri = 0;
        for (int n = 0; n < kN; ++n) {
            if (rel_send[idx * kN + n] > 0.5f) si = n;
            if (rel_rec[idx * kN + n] > 0.5f) ri = n;
        }
        edge_at[ri * kN + si] = idx;
    }
    if (idx < kB * kE) ts[idx] = rel_types[2 * idx] + rel_types[2 * idx + 1];
    if (idx < kH * kH) {
        W2f[idx] = f2h(W2[idx]);
        Wnh[idx] = f2h(Whn[idx]);
        F1[idx] = f2h(fc1w[idx]);
        F2[idx] = f2h(fc2w[idx]);
    }
    if (idx < 512 * 320) {  // Wri = [[Whr|Wir],[Whi|Wii]]  rows x K=320
        int row = idx / 320, k = idx - row * 320;
        float v;
        if (row < 256) v = (k < kH) ? Whr[row * kH + k] : Wir[row * kDin + k - kH];
        else { int o = row - 256; v = (k < kH) ? Whi[o * kH + k] : Wii[o * kDin + k - kH]; }
        Wri[idx] = f2h(v);
    }
    if (idx < kH * kDin) Wnx[idx] = f2h(Win[idx]);
    if (idx < 512 * 256) {  // Wuv: row<256 -> U (W1 cols 0..255), else V
        int row = idx >> 8, k = idx & 255;
        float v = (row < 256) ? W1[row * 512 + k] : W1[(row - 256) * 512 + 256 + k];
        Wuv[idx] = f2h(v);
    }
    if (idx < kDout * kH) F3[idx] = f2h(fc3w[idx]);
    if (idx < 256) bri[idx] = bir[idx] + bhr[idx];
    else if (idx < 512) bri[idx] = bii[idx - 256] + bhi[idx - 256];
}

// ---------------- per-step fused kernel: edge (4 receivers) + their GRU ----
// 256 blocks x 512 thr (8 waves). blockIdx = b*16 + jt; rows m0=blockIdx*4.
__global__ __launch_bounds__(512, 2)
void step_kernel(const float* __restrict__ hprev,
                 const float* __restrict__ inputs, int t,
                 const float* __restrict__ Uin, const float* __restrict__ Vin,
                 const unsigned short* __restrict__ W2f,
                 const float* __restrict__ b1, const float* __restrict__ b2,
                 const float* __restrict__ ts, const int* __restrict__ edge_at,
                 const unsigned short* __restrict__ Wri,
                 const unsigned short* __restrict__ Wnh,
                 const unsigned short* __restrict__ Wnx,
                 const unsigned short* __restrict__ Wuv,
                 const float* __restrict__ bri, const float* __restrict__ bhn,
                 const float* __restrict__ bin_,
                 float* __restrict__ hnew,
                 float* __restrict__ Uo, float* __restrict__ Vo) {
    __shared__ __align__(16) unsigned short h1[kN * kH];   // 32 KiB, swizzled
    __shared__ float vjb[kH];                              // 1 KiB
    __shared__ float tssL[kN];                             // 256 B
    __shared__ float aggL[4][kH];                          // 4 KiB
    __shared__ __align__(16) unsigned short Zf[16 * 320];  // 10 KiB
    __shared__ __align__(16) unsigned short Hf[16 * 256];  // 8 KiB

    const int tid = threadIdx.x;
    const int lane = tid & 63, w = tid >> 6;               // 8 waves
    const int mrow = lane & 15, mq = lane >> 4;
    const int m0 = blockIdx.x * 4;                         // global rows
    const int b = blockIdx.x >> 4, j0 = (blockIdx.x & 15) * 4;

    // ======== PHASE A: edge messages + aggregation for j0..j0+3 ========
    // hoist W2 fragments for this wave's 32 cols (16 x 16B = 64 VGPR), j-invariant
    const unsigned short* Wp = W2f + (size_t)(w * 32 + mrow) * kH + mq * 8;
    half8 bb[8][2];
    #pragma unroll
    for (int kt = 0; kt < 8; ++kt)
        #pragma unroll
        for (int nf = 0; nf < 2; ++nf)
            bb[kt][nf] = *(const half8*)(Wp + nf * 16 * kH + kt * 32);
    __builtin_amdgcn_sched_barrier(0);

    #pragma unroll 1
    for (int jj = 0; jj < 4; ++jj) {
        const int j = j0 + jj;
        if (tid < kN) {
            int e = edge_at[j * kN + tid];
            tssL[tid] = (e < 0) ? 0.f : ts[b * kE + e];
        }
        if (tid < kH) vjb[tid] = Vin[(size_t)(b * kN + j) * kH + tid] + b1[tid];
        __syncthreads();

        // stage h1 = relu(U_i + vjb) as fp16, swizzle byte ^= (row&7)<<4
        {
            const int o = tid & 31, i0 = tid >> 5;   // octet, seed row (0..15)
            const int k0 = o * 8;
            const float4 vj0 = *(const float4*)&vjb[k0];
            const float4 vj1 = *(const float4*)&vjb[k0 + 4];
            #pragma unroll
            for (int p = 0; p < 4; ++p) {
                const int i = i0 + 16 * p;
                const float4* up = (const float4*)(Uin + (size_t)(b * kN + i) * kH + k0);
                float4 f0 = up[0], f1 = up[1];
                float x[8] = {f0.x + vj0.x, f0.y + vj0.y, f0.z + vj0.z, f0.w + vj0.w,
                              f1.x + vj1.x, f1.y + vj1.y, f1.z + vj1.z, f1.w + vj1.w};
                #pragma unroll
                for (int q = 0; q < 8; ++q) x[q] = (i == j) ? 0.f : fmaxf(x[q], 0.f);
                const int byte = i * 512 + ((k0 * 2) ^ ((i & 7) << 4));
                *(uint4*)((char*)h1 + byte) = pack8h(x);
            }
        }
        __syncthreads();

        // MFMA: wave w -> cols [w*32, w*32+32), full M=64
        f32x4 acc[4][2];
        #pragma unroll
        for (int mf = 0; mf < 4; ++mf)
            #pragma unroll
            for (int nf = 0; nf < 2; ++nf) acc[mf][nf] = (f32x4){0.f, 0.f, 0.f, 0.f};
        #pragma unroll
        for (int kt = 0; kt < 8; ++kt) {
            const int k0 = kt * 32;
            half8 a[4];
            #pragma unroll
            for (int mf = 0; mf < 4; ++mf) {
                const int r = mf * 16 + mrow;
                const int byte = r * 512 + (((k0 + mq * 8) * 2) ^ ((r & 7) << 4));
                a[mf] = *(const half8*)((const char*)h1 + byte);
            }
            #pragma unroll
            for (int mf = 0; mf < 4; ++mf)
                #pragma unroll
                for (int nf = 0; nf < 2; ++nf)
                    acc[mf][nf] = __builtin_amdgcn_mfma_f32_16x16x32_f16(
                        a[mf], bb[kt][nf], acc[mf][nf], 0, 0, 0);
        }

        // epilogue: relu(+b2), ts-weight, reduce over senders -> aggL[jj]
        float tsr[16];
        #pragma unroll
        for (int mf = 0; mf < 4; ++mf)
            #pragma unroll
            for (int r = 0; r < 4; ++r)
                tsr[mf * 4 + r] = tssL[mf * 16 + mq * 4 + r];
        #pragma unroll
        for (int nf = 0; nf < 2; ++nf) {
            const int col = w * 32 + nf * 16 + mrow;
            const float bv = b2[col];
            float s = 0.f;
            #pragma unroll
            for (int mf = 0; mf < 4; ++mf)
                #pragma unroll
                for (int r = 0; r < 4; ++r)
                    s += tsr[mf * 4 + r] * fmaxf(acc[mf][nf][r] + bv, 0.f);
            s += __shfl_xor(s, 16);
            s += __shfl_xor(s, 32);
            if (lane < 16) aggL[jj][col] = s;
        }
        __syncthreads();   // aggL done; safe to restage vjb/h1 next jj
    }

    // ======== PHASE B: GRU gates + hnew + U,V for rows m0..m0+3 ========
    // stage Z = [aggL | x] rows 0..3; zero rows 4..15 of Zf and Hf
    {
        const uint4 z4 = {0u, 0u, 0u, 0u};
        for (int c = tid; c < 4 * 40; c += 512) {
            const int r = c / 40, g = c - r * 40;
            float x[8];
            if (g < 32) {
                #pragma unroll
                for (int q = 0; q < 8; ++q) x[q] = aggL[r][g * 8 + q];
            } else {
                const int grow = m0 + r, bb_ = grow >> 6, n = grow & 63;
                const float* xp = inputs + ((size_t)(bb_ * kT + t) * kN + n) * kDin + (g - 32) * 8;
                *(float4*)&x[0] = ((const float4*)xp)[0];
                *(float4*)&x[4] = ((const float4*)xp)[1];
            }
            const int byte = r * 640 + ((g ^ (r & 7)) << 4);
            *(uint4*)((char*)Zf + byte) = pack8h(x);
        }
        for (int c = tid; c < 12 * 40; c += 512) {
            const int r = 4 + c / 40, g = c - (c / 40) * 40;
            const int byte = r * 640 + ((g ^ (r & 7)) << 4);
            *(uint4*)((char*)Zf + byte) = z4;
        }
        for (int c = tid; c < 12 * 32; c += 512) {
            const int r = 4 + c / 32, g = c & 31;
            const int byte = r * 512 + ((g ^ (r & 7)) << 4);
            *(uint4*)((char*)Hf + byte) = z4;
        }
    }
    __syncthreads();

    // GEMM1: 2 nf per wave (8 waves x 32 cols = 256)
    #pragma unroll
    for (int nf = 0; nf < 2; ++nf) {
        const int col = w * 32 + nf * 16 + mrow;
        const unsigned short* WR = Wri + (size_t)col * 320 + mq * 8;
        const unsigned short* WI = Wri + (size_t)(256 + col) * 320 + mq * 8;
        const unsigned short* WNh = Wnh + (size_t)col * kH + mq * 8;
        const unsigned short* WNx = Wnx + (size_t)col * kDin + mq * 8;

        half8 rwa[10][3];
        #pragma unroll
        for (int kt = 0; kt < 10; ++kt) {
            rwa[kt][0] = *(const half8*)(WR + kt * 32);
            rwa[kt][1] = *(const half8*)(WI + kt * 32);
            if (kt < 8) rwa[kt][2] = *(const half8*)(WNh + kt * 32);
            else        rwa[kt][2] = *(const half8*)(WNx + (kt * 32 - 256));
        }
        __builtin_amdgcn_sched_barrier(0);

        f32x4 aR = {0.f,0.f,0.f,0.f}, aI = {0.f,0.f,0.f,0.f};
        f32x4 aNH = {0.f,0.f,0.f,0.f}, aNX = {0.f,0.f,0.f,0.f};
        #pragma unroll
        for (int kt = 0; kt < 10; ++kt) {
            const int g = kt * 4 + mq;
            const int byte = mrow * 640 + ((g ^ (mrow & 7)) << 4);
            half8 zf = *(const half8*)((const char*)Zf + byte);
            aR = __builtin_amdgcn_mfma_f32_16x16x32_f16(zf, rwa[kt][0], aR, 0, 0, 0);
            aI = __builtin_amdgcn_mfma_f32_16x16x32_f16(zf, rwa[kt][1], aI, 0, 0, 0);
            if (kt < 8) aNH = __builtin_amdgcn_mfma_f32_16x16x32_f16(zf, rwa[kt][2], aNH, 0, 0, 0);
            else        aNX = __builtin_amdgcn_mfma_f32_16x16x32_f16(zf, rwa[kt][2], aNX, 0, 0, 0);
        }

        if (mq == 0) {  // D rows 0..3 are the real rows
            const float brv = bri[col], biv = bri[256 + col];
            const float bhnv = bhn[col], binv = bin_[col];
            #pragma unroll
            for (int reg = 0; reg < 4; ++reg) {
                const int lr = reg;
                const int grow = m0 + lr;
                float rg = sigm(aR[reg] + brv);
                float ig = sigm(aI[reg] + biv);
                float ng = tanhf(aNX[reg] + binv + rg * (aNH[reg] + bhnv));
                float h2 = (1.f - ig) * ng + ig * hprev[(size_t)grow * kH + col];
                hnew[(size_t)grow * kH + col] = h2;
                const int byte = lr * 512 + (((col >> 3) ^ (lr & 7)) << 4) + (col & 7) * 2;
                *(unsigned short*)((char*)Hf + byte) = f2h(h2);
            }
        }
    }
    __syncthreads();

    // GEMM2: 4 nf per wave (8 waves x 64 cols = 512) -> U,V
    #pragma unroll
    for (int nf = 0; nf < 4; ++nf) {
        const int col = w * 64 + nf * 16 + mrow;
        const unsigned short* Wp2 = Wuv + (size_t)col * kH + mq * 8;
        half8 rwa[8];
        #pragma unroll
        for (int kt = 0; kt < 8; ++kt) rwa[kt] = *(const half8*)(Wp2 + kt * 32);
        __builtin_amdgcn_sched_barrier(0);
        f32x4 aUV = {0.f, 0.f, 0.f, 0.f};
        #pragma unroll
        for (int kt = 0; kt < 8; ++kt) {
            const int g = kt * 4 + mq;
            const int byte = mrow * 512 + ((g ^ (mrow & 7)) << 4);
            half8 zf = *(const half8*)((const char*)Hf + byte);
            aUV = __builtin_amdgcn_mfma_f32_16x16x32_f16(zf, rwa[kt], aUV, 0, 0, 0);
        }
        if (mq == 0) {
            #pragma unroll
            for (int reg = 0; reg < 4; ++reg) {
                const int grow = m0 + reg;
                const float v = aUV[reg];
                if (col < 256) Uo[(size_t)grow * kH + col] = v;
                else Vo[(size_t)grow * kH + col - 256] = v;
            }
        }
    }
}

// ---------------- batched output MLP (fp16 MFMA), 64 rows/block -------------
__global__ __launch_bounds__(256, 2)
void out_kernel(const float* __restrict__ hist,
                const unsigned short* __restrict__ F1,
                const unsigned short* __restrict__ F2,
                const unsigned short* __restrict__ F3,
                const float* __restrict__ fc1b, const float* __restrict__ fc2b,
                const float* __restrict__ fc3b, float* __restrict__ out) {
    __shared__ __align__(16) unsigned short Af[64 * 256];  // 32 KiB
    __shared__ __align__(16) unsigned short Bf[64 * 256];  // 32 KiB
    const int m0 = blockIdx.x * 64;
    const int tid = threadIdx.x;
    const int lane = tid & 63, w = tid >> 6;
    const int mrow = lane & 15, mq = lane >> 4;

    #pragma unroll
    for (int it = 0; it < 8; ++it) {
        const int c = tid + it * 256;
        const int r = c >> 5, o = c & 31;
        const float* ap = hist + (size_t)(m0 + r) * kH + o * 8;
        float x[8];
        *(float4*)&x[0] = ((const float4*)ap)[0];
        *(float4*)&x[4] = ((const float4*)ap)[1];
        const int byte = r * 512 + ((o << 4) ^ ((r & 7) << 4));
        *(uint4*)((char*)Af + byte) = pack8h(x);
    }
    __syncthreads();

    #define LAYER(SRC, WW, BIAS, DST)                                           \
    {                                                                           \
        const unsigned short* wb = WW + (size_t)(w * 64 + mrow) * kH + mq * 8;  \
        half8 wall[8][4];                                                       \
        _Pragma("unroll")                                                       \
        for (int kt = 0; kt < 8; ++kt)                                          \
            _Pragma("unroll")                                                   \
            for (int nf = 0; nf < 4; ++nf)                                      \
                wall[kt][nf] = *(const half8*)(wb + nf * 16 * kH + kt * 32);    \
        __builtin_amdgcn_sched_barrier(0);                                      \
        f32x4 acc[4][4];                                                        \
        _Pragma("unroll")                                                       \
        for (int m = 0; m < 4; ++m)                                             \
            _Pragma("unroll")                                                   \
            for (int nf = 0; nf < 4; ++nf) acc[m][nf] = (f32x4){0.f,0.f,0.f,0.f};\
        _Pragma("unroll")                                                       \
        for (int kt = 0; kt < 8; ++kt) {                                        \
            const int k0 = kt * 32;                                             \
            half8 zf[4];                                                        \
            _Pragma("unroll")                                                   \
            for (int m = 0; m < 4; ++m) {                                       \
                const int r = m * 16 + mrow;                                    \
                const int byte = r * 512 + (((k0 + mq * 8) * 2) ^ ((r & 7) << 4)); \
                zf[m] = *(const half8*)((const char*)SRC + byte);               \
            }                                                                   \
            _Pragma("unroll")                                                   \
            for (int m = 0; m < 4; ++m)                                         \
                _Pragma("unroll")                                               \
                for (int nf = 0; nf < 4; ++nf)                                  \
                    acc[m][nf] = __builtin_amdgcn_mfma_f32_16x16x32_f16(        \
                        zf[m], wall[kt][nf], acc[m][nf], 0, 0, 0);              \
        }                                                                       \
        _Pragma("unroll")                                                       \
        for (int m = 0; m < 4; ++m)                                             \
            _Pragma("unroll")                                                   \
            for (int nf = 0; nf < 4; ++nf) {                                    \
                const int col = w * 64 + nf * 16 + mrow;                        \
                const float bv = BIAS[col];                                     \
                _Pragma("unroll")                                               \
                for (int reg = 0; reg < 4; ++reg) {                             \
                    const int lr = m * 16 + mq * 4 + reg;                       \
                    float v = fmaxf(acc[m][nf][reg] + bv, 0.f);                 \
                    const int byte = lr * 512 + (((col >> 3) ^ (lr & 7)) << 4) + (col & 7) * 2; \
                    *(unsigned short*)((char*)DST + byte) = f2h(v);             \
                }                                                               \
            }                                                                   \
        __syncthreads();                                                        \
    }

    LAYER(Af, F1, fc1b, Bf)
    LAYER(Bf, F2, fc2b, Af)

    // fc3: N=64, per wave 1 frag of 16 cols, 4 row tiles
    {
        const int row = w * 16 + mrow;
        const unsigned short* wb = F3 + (size_t)row * kH + mq * 8;
        half8 wall[8];
        #pragma unroll
        for (int kt = 0; kt < 8; ++kt) wall[kt] = *(const half8*)(wb + kt * 32);
        __builtin_amdgcn_sched_barrier(0);
        f32x4 acc[4];
        #pragma unroll
        for (int m = 0; m < 4; ++m) acc[m] = (f32x4){0.f, 0.f, 0.f, 0.f};
        #pragma unroll
        for (int kt = 0; kt < 8; ++kt) {
            const int k0 = kt * 32;
            half8 zf[4];
            #pragma unroll
            for (int m = 0; m < 4; ++m) {
                const int r = m * 16 + mrow;
                const int byte = r * 512 + (((k0 + mq * 8) * 2) ^ ((r & 7) << 4));
                zf[m] = *(const half8*)((const char*)Af + byte);
            }
            #pragma unroll
            for (int m = 0; m < 4; ++m)
                acc[m] = __builtin_amdgcn_mfma_f32_16x16x32_f16(zf[m], wall[kt], acc[m], 0, 0, 0);
        }
        const int col = w * 16 + mrow;
        const float bv = fc3b[col];
        #pragma unroll
        for (int m = 0; m < 4; ++m)
            #pragma unroll
            for (int reg = 0; reg < 4; ++reg) {
                const int grow = m0 + m * 16 + mq * 4 + reg;
                const int t = grow >> 10, bn = grow & 1023, b = bn >> 6, n = bn & 63;
                out[(((size_t)b * kTS + t) * kN + n) * kDout + col] = acc[m][reg] + bv;
            }
    }
    #undef LAYER
}

extern "C" void kernel_launch(void* const* d_in, const int* in_sizes, int n_in,
                              void* d_out, int out_size, void* d_ws, size_t ws_size,
                              hipStream_t stream) {
    const float* inputs    = (const float*)d_in[0];
    const float* rel_rec   = (const float*)d_in[1];
    const float* rel_send  = (const float*)d_in[2];
    const float* rel_types = (const float*)d_in[3];
    const float* W1  = (const float*)d_in[4];  const float* b1  = (const float*)d_in[5];
    const float* W2  = (const float*)d_in[6];  const float* b2  = (const float*)d_in[7];
    const float* Wir = (const float*)d_in[8];  const float* bir = (const float*)d_in[9];
    const float* Whr = (const float*)d_in[10]; const float* bhr = (const float*)d_in[11];
    const float* Wii = (const float*)d_in[12]; const float* bii = (const float*)d_in[13];
    const float* Whi = (const float*)d_in[14]; const float* bhi = (const float*)d_in[15];
    const float* Win = (const float*)d_in[16]; const float* bin_ = (const float*)d_in[17];
    const float* Whn = (const float*)d_in[18]; const float* bhn = (const float*)d_in[19];
    const float* fc1w = (const float*)d_in[20]; const float* fc1b = (const float*)d_in[21];
    const float* fc2w = (const float*)d_in[22]; const float* fc2b = (const float*)d_in[23];
    const float* fc3w = (const float*)d_in[24]; const float* fc3b = (const float*)d_in[25];
    float* out = (float*)d_out;

    char* w = (char*)d_ws;
    auto take = [&](size_t bytes) { char* p = w; w += (bytes + 255) & ~(size_t)255; return p; };
    int* edge_at = (int*)take(kN * kN * 4);
    float* ts = (float*)take(kB * kE * 4);
    unsigned short* W2f = (unsigned short*)take(kH * kH * 2);
    unsigned short* Wri = (unsigned short*)take(512 * 320 * 2);
    unsigned short* Wnh = (unsigned short*)take(kH * kH * 2);
    unsigned short* Wnx = (unsigned short*)take(kH * kDin * 2);
    unsigned short* Wuv = (unsigned short*)take(512 * 256 * 2);
    unsigned short* F1 = (unsigned short*)take(kH * kH * 2);
    unsigned short* F2 = (unsigned short*)take(kH * kH * 2);
    unsigned short* F3 = (unsigned short*)take(kDout * kH * 2);
    float* bri = (float*)take(512 * 4);
    float* Ua = (float*)take((size_t)kBN * kH * 4);
    float* Va = (float*)take((size_t)kBN * kH * 4);
    float* Ub = (float*)take((size_t)kBN * kH * 4);
    float* Vb = (float*)take((size_t)kBN * kH * 4);
    float* hh = (float*)w;   // (kTS+1) * kBN * kH floats (~42 MiB)

    hipMemsetAsync(edge_at, 0xFF, kN * kN * 4, stream);
    setup_kernel<<<640, 256, 0, stream>>>(
        rel_rec, rel_send, rel_types, W2, Whr, Whi, Whn, Wir, Wii, Win, W1,
        bir, bhr, bii, bhi, fc1w, fc2w, fc3w,
        edge_at, ts, W2f, Wri, Wnh, Wnx, Wuv, F1, F2, F3, bri);
    hipMemsetAsync(Ua, 0, (size_t)kBN * kH * 4, stream);
    hipMemsetAsync(Va, 0, (size_t)kBN * kH * 4, stream);
    hipMemsetAsync(hh, 0, (size_t)kBN * kH * 4, stream);   // h_0 = 0

    float* Uc = Ua; float* Vc = Va; float* Un = Ub; float* Vn = Vb;
    for (int t = 0; t < kTS; ++t) {
        step_kernel<<<kBN / 4, 512, 0, stream>>>(
            hh + (size_t)t * kBN * kH, inputs, t, Uc, Vc,
            W2f, b1, b2, ts, edge_at, Wri, Wnh, Wnx, Wuv, bri, bhn, bin_,
            hh + (size_t)(t + 1) * kBN * kH, Un, Vn);
        float* tmp;
        tmp = Uc; Uc = Un; Un = tmp;
        tmp = Vc; Vc = Vn; Vn = tmp;
    }
    out_kernel<<<kTS * kBN / 64, 256, 0, stream>>>(
        hh + (size_t)kBN * kH, F1, F2, F3, fc1b, fc2b, fc3b, out);
}